// Round 3
// baseline (5529.744 us; speedup 1.0000x reference)
//
#include <hip/hip_runtime.h>
#include <cmath>

// Problem constants
#define B_   16
#define N_   1024
#define KV_  960
#define H_   2

// ---------------------------------------------------------------------------
// Generic 64x64 tiled f32 GEMM:  C = alpha * op(A) @ op(B)  (+ C if ACCUM)
//   AT=false: A is [M,K] row-major ; AT=true: A is [K,M] row-major (use A^T)
//   BT=false: B is [K,N] row-major ; BT=true: B is [N,K] row-major (use B^T)
// z decodes (b,h): hsel>=0 -> b=z, h=hsel ; hsel<0 -> b=z>>1, h=z&1
// Per-z offsets: X += b*sXb + h*sXh
// All M,Nc multiples of 64; K multiple of 16 (true at every call site).
// ---------------------------------------------------------------------------
template<bool AT, bool BT, bool ACCUM>
__global__ __launch_bounds__(256)
void gemm64(int M, int Nc, int K, float alpha,
            const float* __restrict__ A, int lda, size_t sAb, size_t sAh,
            const float* __restrict__ Bm, int ldb, size_t sBb, size_t sBh,
            float* __restrict__ C, int ldc, size_t sCb, size_t sCh,
            int hsel)
{
    const int z = blockIdx.z;
    int b, h;
    if (hsel >= 0) { b = z; h = hsel; } else { b = z >> 1; h = z & 1; }
    A  += (size_t)b * sAb + (size_t)h * sAh;
    Bm += (size_t)b * sBb + (size_t)h * sBh;
    C  += (size_t)b * sCb + (size_t)h * sCh;

    const int m0 = blockIdx.y * 64;
    const int n0 = blockIdx.x * 64;

    __shared__ float As[16][65];   // [k][m], padded
    __shared__ float Bs[16][65];   // [k][n]

    const int t  = threadIdx.x;
    const int tx = t & 15;
    const int ty = t >> 4;

    float acc[4][4] = {};

    for (int k0 = 0; k0 < K; k0 += 16) {
#pragma unroll
        for (int r = 0; r < 4; ++r) {
            int idx = t + r * 256;                 // 0..1023 covers 16x64
            if (AT) {
                int mm = idx & 63, kk = idx >> 6;
                As[kk][mm] = A[(size_t)(k0 + kk) * lda + (m0 + mm)];
            } else {
                int kk = idx & 15, mm = idx >> 4;
                As[kk][mm] = A[(size_t)(m0 + mm) * lda + (k0 + kk)];
            }
            if (BT) {
                int kk = idx & 15, nn = idx >> 4;
                Bs[kk][nn] = Bm[(size_t)(n0 + nn) * ldb + (k0 + kk)];
            } else {
                int nn = idx & 63, kk = idx >> 6;
                Bs[kk][nn] = Bm[(size_t)(k0 + kk) * ldb + (n0 + nn)];
            }
        }
        __syncthreads();

#pragma unroll
        for (int kk = 0; kk < 16; ++kk) {
            float av[4], bv[4];
#pragma unroll
            for (int i = 0; i < 4; ++i) av[i] = As[kk][ty * 4 + i];
#pragma unroll
            for (int j = 0; j < 4; ++j) bv[j] = Bs[kk][tx * 4 + j];
#pragma unroll
            for (int i = 0; i < 4; ++i)
#pragma unroll
                for (int j = 0; j < 4; ++j)
                    acc[i][j] = fmaf(av[i], bv[j], acc[i][j]);
        }
        __syncthreads();
    }

#pragma unroll
    for (int i = 0; i < 4; ++i) {
        size_t row = (size_t)(m0 + ty * 4 + i) * ldc;
#pragma unroll
        for (int j = 0; j < 4; ++j) {
            size_t o = row + n0 + tx * 4 + j;
            float v = alpha * acc[i][j];
            if (ACCUM) v += C[o];
            C[o] = v;
        }
    }
}

// ---------------------------------------------------------------------------
// InstanceNorm stats PER (b,h,branch): reference normalizes each branch's
// [C_i, 960] score slab separately (InstanceNorm2d over (C_i, KV)).
// grid = NB*2*4 (z = bh*4 + branch), block = 1024.
// stats[2z]=mu, stats[2z+1]=rsqrt(var+eps)
// ---------------------------------------------------------------------------
__global__ __launch_bounds__(1024)
void normstats(const float* __restrict__ S, float* __restrict__ stats)
{
    const int z  = blockIdx.x;
    const int bh = z >> 2, br = z & 3;
    const int row0[4] = {0, 64, 192, 448};
    const int csz [4] = {64, 128, 256, 512};
    const float* p = S + (size_t)bh * (KV_ * KV_) + (size_t)row0[br] * KV_;
    const int n = csz[br] * KV_;

    float s = 0.f, s2 = 0.f;
    for (int i = threadIdx.x; i < n; i += 1024) {
        float v = p[i];
        s += v; s2 += v * v;
    }
#pragma unroll
    for (int o = 32; o; o >>= 1) {
        s  += __shfl_down(s,  o);
        s2 += __shfl_down(s2, o);
    }
    __shared__ float as[16], bs[16];
    int w = threadIdx.x >> 6, l = threadIdx.x & 63;
    if (l == 0) { as[w] = s; bs[w] = s2; }
    __syncthreads();
    if (threadIdx.x == 0) {
        float S1 = 0.f, S2 = 0.f;
        for (int i = 0; i < 16; ++i) { S1 += as[i]; S2 += bs[i]; }
        const float inv_cnt = 1.0f / (float)n;
        float mu  = S1 * inv_cnt;
        float var = S2 * inv_cnt - mu * mu;
        stats[2 * z]     = mu;
        stats[2 * z + 1] = rsqrtf(var + 1e-5f);
    }
}

// ---------------------------------------------------------------------------
// Row softmax over normalized scores, in place. One block per row.
// grid = NB*2*960, block = 256. Branch chosen from row index.
// ---------------------------------------------------------------------------
__global__ __launch_bounds__(256)
void rowsoftmax(float* __restrict__ S, const float* __restrict__ stats)
{
    const size_t r  = blockIdx.x;
    const int bh  = (int)(r / KV_);
    const int row = (int)(r % KV_);
    const int br  = (row < 64) ? 0 : (row < 192) ? 1 : (row < 448) ? 2 : 3;
    const float mu = stats[2 * (bh * 4 + br)];
    const float rs = stats[2 * (bh * 4 + br) + 1];
    float* p = S + r * KV_;

    const int t = threadIdx.x;
    float x[4];
    float mx = -1e30f;
#pragma unroll
    for (int i = 0; i < 4; ++i) {
        int idx = t + i * 256;
        x[i] = (idx < KV_) ? (p[idx] - mu) * rs : -1e30f;
        mx = fmaxf(mx, x[i]);
    }
#pragma unroll
    for (int o = 1; o < 64; o <<= 1) mx = fmaxf(mx, __shfl_xor(mx, o));
    __shared__ float wmax[4], wsum[4];
    int w = t >> 6, l = t & 63;
    if (l == 0) wmax[w] = mx;
    __syncthreads();
    mx = fmaxf(fmaxf(wmax[0], wmax[1]), fmaxf(wmax[2], wmax[3]));

    float s = 0.f;
#pragma unroll
    for (int i = 0; i < 4; ++i) {
        x[i] = expf(x[i] - mx);
        s += x[i];
    }
#pragma unroll
    for (int o = 1; o < 64; o <<= 1) s += __shfl_xor(s, o);
    if (l == 0) wsum[w] = s;
    __syncthreads();
    s = wsum[0] + wsum[1] + wsum[2] + wsum[3];
    float inv = 1.0f / s;
#pragma unroll
    for (int i = 0; i < 4; ++i) {
        int idx = t + i * 256;
        if (idx < KV_) p[idx] = x[i] * inv;
    }
}

// ---------------------------------------------------------------------------
extern "C" void kernel_launch(void* const* d_in, const int* in_sizes, int n_in,
                              void* d_out, int out_size, void* d_ws, size_t ws_size,
                              hipStream_t stream)
{
    const float* emb[4] = {(const float*)d_in[0], (const float*)d_in[1],
                           (const float*)d_in[2], (const float*)d_in[3]};
    const float* emb_all = (const float*)d_in[4];
    const float* Wq[4] = {(const float*)d_in[5], (const float*)d_in[7],
                          (const float*)d_in[9], (const float*)d_in[11]};
    const float* Wo[4] = {(const float*)d_in[6], (const float*)d_in[8],
                          (const float*)d_in[10], (const float*)d_in[12]};
    const float* Wk = (const float*)d_in[13];
    const float* Wv = (const float*)d_in[14];
    float* out = (float*)d_out;

    const int c_sz[4]  = {64, 128, 256, 512};
    const int c_off[4] = {0, 64, 192, 448};

    const size_t BN  = (size_t)N_ * KV_;     // 983040 (per-batch stride, slots A/B)
    const size_t GE  = (size_t)KV_ * KV_;    // 921600 (per-(b,h) stride, slot C)
    const float SCALE = 0.03227486121839514f;  // 1/sqrt(960)

    // Per-batch footprint: slotA (G/ctx) = BN, slotB (Y/V) = 2*BN,
    // slotC (scores) = 2*GE floats -> 19,169,280 B/batch (+ stats).
    const size_t perB = (BN + 2 * BN + 2 * GE) * sizeof(float);
    int NB = 16;
    while (NB > 1 && (size_t)NB * perB + 8192 > ws_size) NB >>= 1;

    for (int b0 = 0; b0 < B_; b0 += NB) {
        char* w = (char*)d_ws;
        float* G     = (float*)w;                                       // [NB][BN]
        float* Yb    = (float*)(w + (size_t)NB * BN * 4);               // [NB][2][BN]
        float* Sc    = (float*)(w + (size_t)NB * 3 * BN * 4);           // [NB][2][GE]
        float* stats = (float*)(w + (size_t)NB * perB);
        float* V     = Yb;   // Y dead after scores
        float* ctx   = G;    // G dead after Y

        // 1) G[b,p,m] = sum_n emb_cat[b,n,p] * emb_all[b,n,m]   (A^T @ B)
        for (int i = 0; i < 4; ++i) {
            gemm64<true, false, false><<<dim3(KV_ / 64, c_sz[i] / 64, NB), 256, 0, stream>>>(
                c_sz[i], KV_, N_, 1.0f,
                emb[i] + (size_t)b0 * N_ * c_sz[i], c_sz[i], (size_t)N_ * c_sz[i], 0,
                emb_all + (size_t)b0 * BN, KV_, BN, 0,
                G + (size_t)c_off[i] * KV_, KV_, BN, 0, /*hsel=*/0);
        }

        // 2) Y[b,h,coff+d,k] = Wq_i[h] @ G_i   (A @ B)
        for (int i = 0; i < 4; ++i) {
            gemm64<false, false, false><<<dim3(KV_ / 64, c_sz[i] / 64, NB * H_), 256, 0, stream>>>(
                c_sz[i], KV_, c_sz[i], 1.0f,
                Wq[i], c_sz[i], 0, (size_t)c_sz[i] * c_sz[i],
                G + (size_t)c_off[i] * KV_, KV_, BN, 0,
                Yb + (size_t)c_off[i] * KV_, KV_, 2 * BN, BN, /*hsel=*/-1);
        }

        // 3) scores[b,h] = SCALE * Y[b,h] @ Wk[h]^T   (A @ B^T)
        gemm64<false, true, false><<<dim3(KV_ / 64, KV_ / 64, NB * H_), 256, 0, stream>>>(
            KV_, KV_, KV_, SCALE,
            Yb, KV_, 2 * BN, BN,
            Wk, KV_, 0, GE,
            Sc, KV_, 2 * GE, GE, /*hsel=*/-1);

        // 4) Per-(b,h,branch) InstanceNorm stats + row softmax (in place)
        normstats<<<NB * H_ * 4, 1024, 0, stream>>>(Sc, stats);
        rowsoftmax<<<NB * H_ * KV_, 256, 0, stream>>>(Sc, stats);

        // 5) V[b,h,n,m] = emb_all[b] @ Wv[h]^T   (A @ B^T) -> Y slot
        gemm64<false, true, false><<<dim3(KV_ / 64, N_ / 64, NB * H_), 256, 0, stream>>>(
            N_, KV_, KV_, 1.0f,
            emb_all + (size_t)b0 * BN, KV_, BN, 0,
            Wv, KV_, 0, GE,
            V, KV_, 2 * BN, BN, /*hsel=*/-1);

        // 6) ctx[b,n,p] = 0.5 * sum_h V[b,h] @ probs[b,h]^T   (A @ B^T, accum h)
        gemm64<false, true, false><<<dim3(KV_ / 64, N_ / 64, NB), 256, 0, stream>>>(
            N_, KV_, KV_, 0.5f,
            V, KV_, 2 * BN, BN,
            Sc, KV_, 2 * GE, GE,
            ctx, KV_, BN, 0, /*hsel=*/0);
        gemm64<false, true, true><<<dim3(KV_ / 64, N_ / 64, NB), 256, 0, stream>>>(
            N_, KV_, KV_, 0.5f,
            V, KV_, 2 * BN, BN,
            Sc, KV_, 2 * GE, GE,
            ctx, KV_, BN, 0, /*hsel=*/1);

        // 7) out[b,n,coff+e] = ctx_i @ Wo_i^T   (A @ B^T)
        for (int i = 0; i < 4; ++i) {
            gemm64<false, true, false><<<dim3(c_sz[i] / 64, N_ / 64, NB), 256, 0, stream>>>(
                N_, c_sz[i], c_sz[i], 1.0f,
                ctx + c_off[i], KV_, BN, 0,
                Wo[i], c_sz[i], 0, 0,
                out + (size_t)b0 * BN + c_off[i], KV_, BN, 0, /*hsel=*/0);
        }
    }
}

// Round 4
// 1467.529 us; speedup vs baseline: 3.7681x; 3.7681x over previous
//
#include <hip/hip_runtime.h>
#include <cmath>

#define B_   16
#define N_   1024
#define KV_  960
#define H_   2

typedef __attribute__((ext_vector_type(8))) short     short8;
typedef __attribute__((ext_vector_type(8))) unsigned short ushort8;
typedef __attribute__((ext_vector_type(4))) unsigned short ushort4v;
typedef __attribute__((ext_vector_type(4))) float     f32x4;
typedef __attribute__((ext_vector_type(4))) float     float4v;

__device__ inline ushort f2b(float f) {
    union { float f; unsigned u; } x; x.f = f;
    unsigned r = x.u + 0x7FFFu + ((x.u >> 16) & 1u);   // RNE
    return (ushort)(r >> 16);
}

// ---------------------------------------------------------------------------
// Stage a 64(row)x64(k) bf16 tile into LDS [64][72] (ushort, 144B row stride).
//   TR=false: src is [R][K] row-major (k-contiguous)   -> vector b128 writes
//   TR=true : src is [K][R] row-major (r-contiguous)   -> scalar u16 scatter
//   F32S: source is f32, convert inline.
// ---------------------------------------------------------------------------
template<bool TR, bool F32S>
__device__ inline void stage64(const void* __restrict__ src, int ld, int r0, int k0,
                               ushort* __restrict__ lds, int t)
{
#pragma unroll
    for (int rep = 0; rep < 2; ++rep) {
        int idx = t + rep * 256;                      // 0..511, 8 elts each
        if (!TR) {
            int rr = idx >> 3, kc = (idx & 7) << 3;
            ushort8 v;
            if (F32S) {
                const float* s = (const float*)src + (size_t)(r0 + rr) * ld + (k0 + kc);
                float4v f0 = *(const float4v*)s;
                float4v f1 = *(const float4v*)(s + 4);
                v[0] = f2b(f0[0]); v[1] = f2b(f0[1]); v[2] = f2b(f0[2]); v[3] = f2b(f0[3]);
                v[4] = f2b(f1[0]); v[5] = f2b(f1[1]); v[6] = f2b(f1[2]); v[7] = f2b(f1[3]);
            } else {
                v = *(const ushort8*)((const ushort*)src + (size_t)(r0 + rr) * ld + (k0 + kc));
            }
            *(ushort8*)&lds[rr * 72 + kc] = v;
        } else {
            int kk = idx >> 3, rc = (idx & 7) << 3;
            ushort tmp[8];
            if (F32S) {
                const float* s = (const float*)src + (size_t)(k0 + kk) * ld + (r0 + rc);
                float4v f0 = *(const float4v*)s;
                float4v f1 = *(const float4v*)(s + 4);
                tmp[0] = f2b(f0[0]); tmp[1] = f2b(f0[1]); tmp[2] = f2b(f0[2]); tmp[3] = f2b(f0[3]);
                tmp[4] = f2b(f1[0]); tmp[5] = f2b(f1[1]); tmp[6] = f2b(f1[2]); tmp[7] = f2b(f1[3]);
            } else {
                const ushort* s = (const ushort*)src + (size_t)(k0 + kk) * ld + (r0 + rc);
                ushort8 v = *(const ushort8*)s;
#pragma unroll
                for (int j = 0; j < 8; ++j) tmp[j] = v[j];
            }
#pragma unroll
            for (int j = 0; j < 8; ++j) lds[(rc + j) * 72 + kk] = tmp[j];
        }
    }
}

// ---------------------------------------------------------------------------
// 64x64-tile bf16 MFMA GEMM:  C = alpha * op(A) @ op(B)^T-ish
//   A direct: [M][K]; ATR: A is [K][M].  B direct: [N][K]; BTR: B is [K][N].
//   HSUM=2: sum over h of A_h @ B_h (pointer strides sAh/sBh), epilogue h=hsel.
//   OUTF32: write f32, else bf16. Strides in ELEMENTS of respective dtype.
// grid: (Nc/64, M/64, z) ; block 256 (4 waves, 2x2, 32x32 each).
// ---------------------------------------------------------------------------
template<bool ATR, bool BTR, bool AF32, bool BF32, int HSUM, bool OUTF32>
__global__ __launch_bounds__(256)
void mgemm(int M, int Nc, int K, float alpha,
           const void* __restrict__ A, int lda, size_t sAb, size_t sAh,
           const void* __restrict__ Bm, int ldb, size_t sBb, size_t sBh,
           void* __restrict__ C, int ldc, size_t sCb, size_t sCh, int hsel)
{
    __shared__ ushort As[64 * 72];
    __shared__ ushort Bs[64 * 72];
    const int z = blockIdx.z;
    int b, h;
    if (hsel >= 0) { b = z; h = hsel; } else { b = z >> 1; h = z & 1; }
    const int m0 = blockIdx.y * 64, n0 = blockIdx.x * 64;
    const int t = threadIdx.x;
    const int lane = t & 63, wave = t >> 6;
    const int wr = wave >> 1, wc = wave & 1;

    f32x4 zero4 = {0.f, 0.f, 0.f, 0.f};
    f32x4 acc[2][2];
    acc[0][0] = zero4; acc[0][1] = zero4; acc[1][0] = zero4; acc[1][1] = zero4;

    for (int hh = 0; hh < HSUM; ++hh) {
        const int he = (HSUM == 2) ? hh : h;
        const char* Ab = (const char*)A + ((size_t)b * sAb + (size_t)he * sAh) * (AF32 ? 4 : 2);
        const char* Bb = (const char*)Bm + ((size_t)b * sBb + (size_t)he * sBh) * (BF32 ? 4 : 2);
        for (int k0 = 0; k0 < K; k0 += 64) {
            stage64<ATR, AF32>(Ab, lda, m0, k0, As, t);
            stage64<BTR, BF32>(Bb, ldb, n0, k0, Bs, t);
            __syncthreads();
            const int ar = wr * 32 + (lane & 15);
            const int br = wc * 32 + (lane & 15);
            const int kg = (lane >> 4) * 8;
#pragma unroll
            for (int ks = 0; ks < 2; ++ks) {
                short8 a0 = *(const short8*)&As[(ar)      * 72 + ks * 32 + kg];
                short8 a1 = *(const short8*)&As[(ar + 16) * 72 + ks * 32 + kg];
                short8 b0 = *(const short8*)&Bs[(br)      * 72 + ks * 32 + kg];
                short8 b1 = *(const short8*)&Bs[(br + 16) * 72 + ks * 32 + kg];
                acc[0][0] = __builtin_amdgcn_mfma_f32_16x16x32_bf16(a0, b0, acc[0][0], 0, 0, 0);
                acc[0][1] = __builtin_amdgcn_mfma_f32_16x16x32_bf16(a0, b1, acc[0][1], 0, 0, 0);
                acc[1][0] = __builtin_amdgcn_mfma_f32_16x16x32_bf16(a1, b0, acc[1][0], 0, 0, 0);
                acc[1][1] = __builtin_amdgcn_mfma_f32_16x16x32_bf16(a1, b1, acc[1][1], 0, 0, 0);
            }
            __syncthreads();
        }
    }

    char* Cb = (char*)C + ((size_t)b * sCb + (size_t)h * sCh) * (OUTF32 ? 4 : 2);
#pragma unroll
    for (int i = 0; i < 2; ++i)
#pragma unroll
        for (int q = 0; q < 4; ++q) {
            int row = m0 + wr * 32 + i * 16 + (lane >> 4) * 4 + q;
#pragma unroll
            for (int j = 0; j < 2; ++j) {
                int col = n0 + wc * 32 + j * 16 + (lane & 15);
                float v = alpha * acc[i][j][q];
                if (OUTF32) ((float*)Cb)[(size_t)row * ldc + col] = v;
                else        ((ushort*)Cb)[(size_t)row * ldc + col] = f2b(v);
            }
        }
}

// ---------------------------------------------------------------------------
// f32 -> bf16 bulk convert (n % 4 == 0)
// ---------------------------------------------------------------------------
__global__ __launch_bounds__(256)
void cvtf2b(const float* __restrict__ s, ushort* __restrict__ d, size_t n)
{
    size_t i = ((size_t)blockIdx.x * 256 + threadIdx.x) * 4;
    size_t stride = (size_t)gridDim.x * 1024;
    for (; i < n; i += stride) {
        float4v f = *(const float4v*)(s + i);
        ushort4v v;
        v[0] = f2b(f[0]); v[1] = f2b(f[1]); v[2] = f2b(f[2]); v[3] = f2b(f[3]);
        *(ushort4v*)(d + i) = v;
    }
}

// ---------------------------------------------------------------------------
// InstanceNorm stats PER (b,h,branch). grid = NB*2*4, block = 1024.
// ---------------------------------------------------------------------------
__global__ __launch_bounds__(1024)
void normstats(const float* __restrict__ S, float* __restrict__ stats)
{
    const int z  = blockIdx.x;
    const int bh = z >> 2, br = z & 3;
    const int row0[4] = {0, 64, 192, 448};
    const int csz [4] = {64, 128, 256, 512};
    const float* p = S + (size_t)bh * (KV_ * KV_) + (size_t)row0[br] * KV_;
    const int n = csz[br] * KV_;

    float s = 0.f, s2 = 0.f;
    for (int i = threadIdx.x; i < n; i += 1024) {
        float v = p[i];
        s += v; s2 += v * v;
    }
#pragma unroll
    for (int o = 32; o; o >>= 1) {
        s  += __shfl_down(s,  o);
        s2 += __shfl_down(s2, o);
    }
    __shared__ float as[16], bs[16];
    int w = threadIdx.x >> 6, l = threadIdx.x & 63;
    if (l == 0) { as[w] = s; bs[w] = s2; }
    __syncthreads();
    if (threadIdx.x == 0) {
        float S1 = 0.f, S2 = 0.f;
        for (int i = 0; i < 16; ++i) { S1 += as[i]; S2 += bs[i]; }
        const float inv_cnt = 1.0f / (float)n;
        float mu  = S1 * inv_cnt;
        float var = S2 * inv_cnt - mu * mu;
        stats[2 * z]     = mu;
        stats[2 * z + 1] = rsqrtf(var + 1e-5f);
    }
}

// ---------------------------------------------------------------------------
// Row softmax of normalized scores: read f32 S, write bf16 P.
// grid = NB*2*960, block = 256.
// ---------------------------------------------------------------------------
__global__ __launch_bounds__(256)
void psoftmax(const float* __restrict__ S, ushort* __restrict__ P,
              const float* __restrict__ stats)
{
    const size_t r  = blockIdx.x;
    const int bh  = (int)(r / KV_);
    const int row = (int)(r % KV_);
    const int br  = (row < 64) ? 0 : (row < 192) ? 1 : (row < 448) ? 2 : 3;
    const float mu = stats[2 * (bh * 4 + br)];
    const float rs = stats[2 * (bh * 4 + br) + 1];
    const float* p = S + r * KV_;
    ushort* q = P + r * KV_;

    const int t = threadIdx.x;
    float x[4];
    float mx = -1e30f;
#pragma unroll
    for (int i = 0; i < 4; ++i) {
        int idx = t + i * 256;
        x[i] = (idx < KV_) ? (p[idx] - mu) * rs : -1e30f;
        mx = fmaxf(mx, x[i]);
    }
#pragma unroll
    for (int o = 1; o < 64; o <<= 1) mx = fmaxf(mx, __shfl_xor(mx, o));
    __shared__ float wmax[4], wsum[4];
    int w = t >> 6, l = t & 63;
    if (l == 0) wmax[w] = mx;
    __syncthreads();
    mx = fmaxf(fmaxf(wmax[0], wmax[1]), fmaxf(wmax[2], wmax[3]));

    float s = 0.f;
#pragma unroll
    for (int i = 0; i < 4; ++i) {
        x[i] = expf(x[i] - mx);
        s += x[i];
    }
#pragma unroll
    for (int o = 1; o < 64; o <<= 1) s += __shfl_xor(s, o);
    if (l == 0) wsum[w] = s;
    __syncthreads();
    s = wsum[0] + wsum[1] + wsum[2] + wsum[3];
    float inv = 1.0f / s;
#pragma unroll
    for (int i = 0; i < 4; ++i) {
        int idx = t + i * 256;
        if (idx < KV_) q[idx] = f2b(x[i] * inv);
    }
}

// ---------------------------------------------------------------------------
extern "C" void kernel_launch(void* const* d_in, const int* in_sizes, int n_in,
                              void* d_out, int out_size, void* d_ws, size_t ws_size,
                              hipStream_t stream)
{
    const float* emb[4] = {(const float*)d_in[0], (const float*)d_in[1],
                           (const float*)d_in[2], (const float*)d_in[3]};
    const float* emb_all = (const float*)d_in[4];
    const float* Wq[4] = {(const float*)d_in[5], (const float*)d_in[7],
                          (const float*)d_in[9], (const float*)d_in[11]};
    const float* Wo[4] = {(const float*)d_in[6], (const float*)d_in[8],
                          (const float*)d_in[10], (const float*)d_in[12]};
    const float* Wk = (const float*)d_in[13];
    const float* Wv = (const float*)d_in[14];
    float* out = (float*)d_out;

    const int c_sz[4]  = {64, 128, 256, 512};
    const int c_off[4] = {0, 64, 192, 448};

    const size_t BN = (size_t)N_ * KV_;   // 983040
    const size_t GE = (size_t)KV_ * KV_;  // 921600
    const float SCALE = 0.03227486121839514f;  // 1/sqrt(960)

    // ---- bump allocator on d_ws
    char* wsp = (char*)d_ws;
    size_t off = 0;
    auto alloc = [&](size_t bytes) -> char* {
        off = (off + 255) & ~(size_t)255;
        char* p = wsp + off;
        off += bytes;
        return p;
    };

    // Static: bf16 weights
    ushort* WqB[4]; ushort* WoB[4];
    for (int i = 0; i < 4; ++i) WqB[i] = (ushort*)alloc((size_t)2 * c_sz[i] * c_sz[i] * 2);
    for (int i = 0; i < 4; ++i) WoB[i] = (ushort*)alloc((size_t)c_sz[i] * c_sz[i] * 2);
    ushort* WkB = (ushort*)alloc((size_t)2 * GE * 2);
    ushort* WvB = (ushort*)alloc((size_t)2 * GE * 2);

    for (int i = 0; i < 4; ++i) {
        size_t n = (size_t)2 * c_sz[i] * c_sz[i];
        cvtf2b<<<dim3((unsigned)((n / 4 + 255) / 256)), 256, 0, stream>>>(Wq[i], WqB[i], n);
        n = (size_t)c_sz[i] * c_sz[i];
        cvtf2b<<<dim3((unsigned)((n / 4 + 255) / 256)), 256, 0, stream>>>(Wo[i], WoB[i], n);
    }
    cvtf2b<<<dim3(1800), 256, 0, stream>>>(Wk, WkB, 2 * GE);
    cvtf2b<<<dim3(1800), 256, 0, stream>>>(Wv, WvB, 2 * GE);

    // Per-batch dynamic slots (bytes): A: bf16 BN ; B: bf16 2*BN ; Sc: f32 2*GE ; P: bf16 2*GE
    const size_t perB = BN * 2 + 2 * BN * 2 + 2 * GE * 4 + 2 * GE * 2;  // 16,957,440
    size_t statik = (off + 255) & ~(size_t)255;
    int NB = 16;
    while (NB > 1 && statik + (size_t)NB * perB + 65536 > ws_size) NB >>= 1;

    ushort* slotA = (ushort*)alloc((size_t)NB * BN * 2);          // G / ctx
    ushort* slotB = (ushort*)alloc((size_t)NB * 2 * BN * 2);      // Y / V
    float*  Sc    = (float*) alloc((size_t)NB * 2 * GE * 4);      // scores f32
    ushort* P     = (ushort*)alloc((size_t)NB * 2 * GE * 2);      // probs bf16
    float*  stats = (float*) alloc((size_t)NB * 2 * 4 * 2 * 4);

    for (int b0 = 0; b0 < B_; b0 += NB) {
        // 1) G[b,p,m] = emb_cat^T @ emb_all  (both operands [K=n][R]) -> bf16
        for (int i = 0; i < 4; ++i) {
            mgemm<true, true, true, true, 1, false>
                <<<dim3(KV_ / 64, c_sz[i] / 64, NB), 256, 0, stream>>>(
                c_sz[i], KV_, N_, 1.0f,
                emb[i] + (size_t)b0 * N_ * c_sz[i], c_sz[i], (size_t)N_ * c_sz[i], 0,
                emb_all + (size_t)b0 * BN, KV_, BN, 0,
                slotA + (size_t)c_off[i] * KV_, KV_, BN, 0, /*hsel=*/0);
        }

        // 2) Y[b,h] rows c_off.. = Wq_i[h] @ G_i   (B = G is [K=p][N=m])
        for (int i = 0; i < 4; ++i) {
            mgemm<false, true, false, false, 1, false>
                <<<dim3(KV_ / 64, c_sz[i] / 64, NB * H_), 256, 0, stream>>>(
                c_sz[i], KV_, c_sz[i], 1.0f,
                WqB[i], c_sz[i], 0, (size_t)c_sz[i] * c_sz[i],
                slotA + (size_t)c_off[i] * KV_, KV_, BN, 0,
                slotB + (size_t)c_off[i] * KV_, KV_, 2 * BN, BN, /*hsel=*/-1);
        }

        // 3) scores f32 = SCALE * Y @ Wk[h]^T   (all direct)
        mgemm<false, false, false, false, 1, true>
            <<<dim3(KV_ / 64, KV_ / 64, NB * H_), 256, 0, stream>>>(
            KV_, KV_, KV_, SCALE,
            slotB, KV_, 2 * BN, BN,
            WkB, KV_, 0, GE,
            Sc, KV_, 2 * GE, GE, /*hsel=*/-1);

        // 4) per-(b,h,branch) stats + softmax -> P bf16
        normstats<<<NB * H_ * 4, 1024, 0, stream>>>(Sc, stats);
        psoftmax<<<NB * H_ * KV_, 256, 0, stream>>>(Sc, P, stats);

        // 5) V bf16 = emb_all @ Wv[h]^T   (A f32 direct, B direct)
        mgemm<false, false, true, false, 1, false>
            <<<dim3(KV_ / 64, N_ / 64, NB * H_), 256, 0, stream>>>(
            N_, KV_, KV_, 1.0f,
            emb_all + (size_t)b0 * BN, KV_, BN, 0,
            WvB, KV_, 0, GE,
            slotB, KV_, 2 * BN, BN, /*hsel=*/-1);

        // 6) ctx bf16 = 0.5 * sum_h V[h] @ P[h]^T   (HSUM=2)
        mgemm<false, false, false, false, 2, false>
            <<<dim3(KV_ / 64, N_ / 64, NB), 256, 0, stream>>>(
            N_, KV_, KV_, 0.5f,
            slotB, KV_, 2 * BN, BN,
            P, KV_, 2 * GE, GE,
            slotA, KV_, BN, 0, /*hsel=*/0);

        // 7) out f32 = ctx_i @ Wo_i^T
        for (int i = 0; i < 4; ++i) {
            mgemm<false, false, false, false, 1, true>
                <<<dim3(c_sz[i] / 64, N_ / 64, NB), 256, 0, stream>>>(
                N_, c_sz[i], c_sz[i], 1.0f,
                slotA + c_off[i], KV_, BN, 0,
                WoB[i], c_sz[i], 0, 0,
                out + (size_t)b0 * BN + c_off[i], KV_, BN, 0, /*hsel=*/0);
        }
    }
}

// Round 5
// 1259.905 us; speedup vs baseline: 4.3890x; 1.1648x over previous
//
#include <hip/hip_runtime.h>
#include <cmath>

#define B_   16
#define N_   1024
#define KV_  960
#define H_   2

typedef __attribute__((ext_vector_type(8))) short     short8;
typedef __attribute__((ext_vector_type(8))) unsigned short ushort8;
typedef __attribute__((ext_vector_type(4))) unsigned short ushort4v;
typedef __attribute__((ext_vector_type(4))) float     f32x4;
typedef __attribute__((ext_vector_type(4))) float     float4v;
typedef __attribute__((ext_vector_type(2))) float     float2v;

__device__ inline ushort f2b(float f) {
    union { float f; unsigned u; } x; x.f = f;
    unsigned r = x.u + 0x7FFFu + ((x.u >> 16) & 1u);   // RNE
    return (ushort)(r >> 16);
}

// ---------------------------------------------------------------------------
// Stage a 64(row)x64(k) bf16 tile into LDS [64][72] (ushort, 144B row stride).
// ---------------------------------------------------------------------------
template<bool TR, bool F32S>
__device__ inline void stage64(const void* __restrict__ src, int ld, int r0, int k0,
                               ushort* __restrict__ lds, int t)
{
#pragma unroll
    for (int rep = 0; rep < 2; ++rep) {
        int idx = t + rep * 256;                      // 0..511, 8 elts each
        if (!TR) {
            int rr = idx >> 3, kc = (idx & 7) << 3;
            ushort8 v;
            if (F32S) {
                const float* s = (const float*)src + (size_t)(r0 + rr) * ld + (k0 + kc);
                float4v f0 = *(const float4v*)s;
                float4v f1 = *(const float4v*)(s + 4);
                v[0] = f2b(f0[0]); v[1] = f2b(f0[1]); v[2] = f2b(f0[2]); v[3] = f2b(f0[3]);
                v[4] = f2b(f1[0]); v[5] = f2b(f1[1]); v[6] = f2b(f1[2]); v[7] = f2b(f1[3]);
            } else {
                v = *(const ushort8*)((const ushort*)src + (size_t)(r0 + rr) * ld + (k0 + kc));
            }
            *(ushort8*)&lds[rr * 72 + kc] = v;
        } else {
            int kk = idx >> 3, rc = (idx & 7) << 3;
            ushort tmp[8];
            if (F32S) {
                const float* s = (const float*)src + (size_t)(k0 + kk) * ld + (r0 + rc);
                float4v f0 = *(const float4v*)s;
                float4v f1 = *(const float4v*)(s + 4);
                tmp[0] = f2b(f0[0]); tmp[1] = f2b(f0[1]); tmp[2] = f2b(f0[2]); tmp[3] = f2b(f0[3]);
                tmp[4] = f2b(f1[0]); tmp[5] = f2b(f1[1]); tmp[6] = f2b(f1[2]); tmp[7] = f2b(f1[3]);
            } else {
                const ushort* s = (const ushort*)src + (size_t)(k0 + kk) * ld + (r0 + rc);
                ushort8 v = *(const ushort8*)s;
#pragma unroll
                for (int j = 0; j < 8; ++j) tmp[j] = v[j];
            }
#pragma unroll
            for (int j = 0; j < 8; ++j) lds[(rc + j) * 72 + kk] = tmp[j];
        }
    }
}

// ---------------------------------------------------------------------------
// 64x64-tile bf16 MFMA GEMM (unchanged from R4).
// ---------------------------------------------------------------------------
template<bool ATR, bool BTR, bool AF32, bool BF32, int HSUM, bool OUTF32>
__global__ __launch_bounds__(256)
void mgemm(int M, int Nc, int K, float alpha,
           const void* __restrict__ A, int lda, size_t sAb, size_t sAh,
           const void* __restrict__ Bm, int ldb, size_t sBb, size_t sBh,
           void* __restrict__ C, int ldc, size_t sCb, size_t sCh, int hsel)
{
    __shared__ ushort As[64 * 72];
    __shared__ ushort Bs[64 * 72];
    const int z = blockIdx.z;
    int b, h;
    if (hsel >= 0) { b = z; h = hsel; } else { b = z >> 1; h = z & 1; }
    const int m0 = blockIdx.y * 64, n0 = blockIdx.x * 64;
    const int t = threadIdx.x;
    const int lane = t & 63, wave = t >> 6;
    const int wr = wave >> 1, wc = wave & 1;

    f32x4 zero4 = {0.f, 0.f, 0.f, 0.f};
    f32x4 acc[2][2];
    acc[0][0] = zero4; acc[0][1] = zero4; acc[1][0] = zero4; acc[1][1] = zero4;

    for (int hh = 0; hh < HSUM; ++hh) {
        const int he = (HSUM == 2) ? hh : h;
        const char* Ab = (const char*)A + ((size_t)b * sAb + (size_t)he * sAh) * (AF32 ? 4 : 2);
        const char* Bb = (const char*)Bm + ((size_t)b * sBb + (size_t)he * sBh) * (BF32 ? 4 : 2);
        for (int k0 = 0; k0 < K; k0 += 64) {
            stage64<ATR, AF32>(Ab, lda, m0, k0, As, t);
            stage64<BTR, BF32>(Bb, ldb, n0, k0, Bs, t);
            __syncthreads();
            const int ar = wr * 32 + (lane & 15);
            const int br = wc * 32 + (lane & 15);
            const int kg = (lane >> 4) * 8;
#pragma unroll
            for (int ks = 0; ks < 2; ++ks) {
                short8 a0 = *(const short8*)&As[(ar)      * 72 + ks * 32 + kg];
                short8 a1 = *(const short8*)&As[(ar + 16) * 72 + ks * 32 + kg];
                short8 b0 = *(const short8*)&Bs[(br)      * 72 + ks * 32 + kg];
                short8 b1 = *(const short8*)&Bs[(br + 16) * 72 + ks * 32 + kg];
                acc[0][0] = __builtin_amdgcn_mfma_f32_16x16x32_bf16(a0, b0, acc[0][0], 0, 0, 0);
                acc[0][1] = __builtin_amdgcn_mfma_f32_16x16x32_bf16(a0, b1, acc[0][1], 0, 0, 0);
                acc[1][0] = __builtin_amdgcn_mfma_f32_16x16x32_bf16(a1, b0, acc[1][0], 0, 0, 0);
                acc[1][1] = __builtin_amdgcn_mfma_f32_16x16x32_bf16(a1, b1, acc[1][1], 0, 0, 0);
            }
            __syncthreads();
        }
    }

    char* Cb = (char*)C + ((size_t)b * sCb + (size_t)h * sCh) * (OUTF32 ? 4 : 2);
#pragma unroll
    for (int i = 0; i < 2; ++i)
#pragma unroll
        for (int q = 0; q < 4; ++q) {
            int row = m0 + wr * 32 + i * 16 + (lane >> 4) * 4 + q;
#pragma unroll
            for (int j = 0; j < 2; ++j) {
                int col = n0 + wc * 32 + j * 16 + (lane & 15);
                float v = alpha * acc[i][j][q];
                if (OUTF32) ((float*)Cb)[(size_t)row * ldc + col] = v;
                else        ((ushort*)Cb)[(size_t)row * ldc + col] = f2b(v);
            }
        }
}

// ---------------------------------------------------------------------------
// f32 -> bf16 bulk convert (n % 4 == 0)
// ---------------------------------------------------------------------------
__global__ __launch_bounds__(256)
void cvtf2b(const float* __restrict__ s, ushort* __restrict__ d, size_t n)
{
    size_t i = ((size_t)blockIdx.x * 256 + threadIdx.x) * 4;
    size_t stride = (size_t)gridDim.x * 1024;
    for (; i < n; i += stride) {
        float4v f = *(const float4v*)(s + i);
        ushort4v v;
        v[0] = f2b(f[0]); v[1] = f2b(f[1]); v[2] = f2b(f[2]); v[3] = f2b(f[3]);
        *(ushort4v*)(d + i) = v;
    }
}

// ---------------------------------------------------------------------------
// InstanceNorm stats, two-stage deterministic reduction.
// Stage 1: grid (z = bh*4+br, chunk<8), 256 thr. Each block reduces one
//          64-row chunk (64*960 f32) of its branch slab -> float2 partial.
// Stage 2: grid z, 64 thr; thread 0 combines <=8 partials -> stats.
// ---------------------------------------------------------------------------
__global__ __launch_bounds__(256)
void normstats1(const float* __restrict__ S, float2v* __restrict__ partials)
{
    const int z = blockIdx.x, chunk = blockIdx.y;
    const int bh = z >> 2, br = z & 3;
    const int row0[4] = {0, 64, 192, 448};
    const int nch [4] = {1, 2, 4, 8};
    if (chunk >= nch[br]) return;
    const float* p = S + (size_t)bh * (KV_ * KV_)
                       + (size_t)(row0[br] + chunk * 64) * KV_;
    float s = 0.f, s2 = 0.f;
    // 64*960 = 61440 floats; 256 threads * float4 strided
    for (int i = threadIdx.x * 4; i < 64 * KV_; i += 1024) {
        float4v f = *(const float4v*)(p + i);
#pragma unroll
        for (int j = 0; j < 4; ++j) { s += f[j]; s2 += f[j] * f[j]; }
    }
#pragma unroll
    for (int o = 32; o; o >>= 1) {
        s  += __shfl_down(s,  o);
        s2 += __shfl_down(s2, o);
    }
    __shared__ float as[4], bs[4];
    int w = threadIdx.x >> 6, l = threadIdx.x & 63;
    if (l == 0) { as[w] = s; bs[w] = s2; }
    __syncthreads();
    if (threadIdx.x == 0) {
        float2v r;
        r[0] = as[0] + as[1] + as[2] + as[3];
        r[1] = bs[0] + bs[1] + bs[2] + bs[3];
        partials[z * 8 + chunk] = r;
    }
}

__global__ __launch_bounds__(64)
void normstats2(const float2v* __restrict__ partials, float* __restrict__ stats)
{
    const int z = blockIdx.x;
    const int br = z & 3;
    const int nch[4] = {1, 2, 4, 8};
    const int csz[4] = {64, 128, 256, 512};
    if (threadIdx.x == 0) {
        float s = 0.f, s2 = 0.f;
        for (int i = 0; i < nch[br]; ++i) {
            float2v r = partials[z * 8 + i];
            s += r[0]; s2 += r[1];
        }
        const float inv_cnt = 1.0f / (float)(csz[br] * KV_);
        float mu  = s * inv_cnt;
        float var = s2 * inv_cnt - mu * mu;
        stats[2 * z]     = mu;
        stats[2 * z + 1] = rsqrtf(var + 1e-5f);
    }
}

// ---------------------------------------------------------------------------
// Row softmax of normalized scores: read f32 S, write bf16 P.
// grid = NB*2*960, block = 256.
// ---------------------------------------------------------------------------
__global__ __launch_bounds__(256)
void psoftmax(const float* __restrict__ S, ushort* __restrict__ P,
              const float* __restrict__ stats)
{
    const size_t r  = blockIdx.x;
    const int bh  = (int)(r / KV_);
    const int row = (int)(r % KV_);
    const int br  = (row < 64) ? 0 : (row < 192) ? 1 : (row < 448) ? 2 : 3;
    const float mu = stats[2 * (bh * 4 + br)];
    const float rs = stats[2 * (bh * 4 + br) + 1];
    const float* p = S + r * KV_;
    ushort* q = P + r * KV_;

    const int t = threadIdx.x;
    float x[4];
    float mx = -1e30f;
#pragma unroll
    for (int i = 0; i < 4; ++i) {
        int idx = t + i * 256;
        x[i] = (idx < KV_) ? (p[idx] - mu) * rs : -1e30f;
        mx = fmaxf(mx, x[i]);
    }
#pragma unroll
    for (int o = 1; o < 64; o <<= 1) mx = fmaxf(mx, __shfl_xor(mx, o));
    __shared__ float wmax[4], wsum[4];
    int w = t >> 6, l = t & 63;
    if (l == 0) wmax[w] = mx;
    __syncthreads();
    mx = fmaxf(fmaxf(wmax[0], wmax[1]), fmaxf(wmax[2], wmax[3]));

    float s = 0.f;
#pragma unroll
    for (int i = 0; i < 4; ++i) {
        x[i] = expf(x[i] - mx);
        s += x[i];
    }
#pragma unroll
    for (int o = 1; o < 64; o <<= 1) s += __shfl_xor(s, o);
    if (l == 0) wsum[w] = s;
    __syncthreads();
    s = wsum[0] + wsum[1] + wsum[2] + wsum[3];
    float inv = 1.0f / s;
#pragma unroll
    for (int i = 0; i < 4; ++i) {
        int idx = t + i * 256;
        if (idx < KV_) q[idx] = f2b(x[i] * inv);
    }
}

// ---------------------------------------------------------------------------
extern "C" void kernel_launch(void* const* d_in, const int* in_sizes, int n_in,
                              void* d_out, int out_size, void* d_ws, size_t ws_size,
                              hipStream_t stream)
{
    const float* emb[4] = {(const float*)d_in[0], (const float*)d_in[1],
                           (const float*)d_in[2], (const float*)d_in[3]};
    const float* emb_all = (const float*)d_in[4];
    const float* Wq[4] = {(const float*)d_in[5], (const float*)d_in[7],
                          (const float*)d_in[9], (const float*)d_in[11]};
    const float* Wo[4] = {(const float*)d_in[6], (const float*)d_in[8],
                          (const float*)d_in[10], (const float*)d_in[12]};
    const float* Wk = (const float*)d_in[13];
    const float* Wv = (const float*)d_in[14];
    float* out = (float*)d_out;

    const int c_sz[4]  = {64, 128, 256, 512};
    const int c_off[4] = {0, 64, 192, 448};

    const size_t BN = (size_t)N_ * KV_;   // 983040
    const size_t GE = (size_t)KV_ * KV_;  // 921600
    const float SCALE = 0.03227486121839514f;  // 1/sqrt(960)

    // ---- bump allocator on d_ws
    char* wsp = (char*)d_ws;
    size_t off = 0;
    auto alloc = [&](size_t bytes) -> char* {
        off = (off + 255) & ~(size_t)255;
        char* p = wsp + off;
        off += bytes;
        return p;
    };

    // Static: bf16 weights
    ushort* WqB[4]; ushort* WoB[4];
    for (int i = 0; i < 4; ++i) WqB[i] = (ushort*)alloc((size_t)2 * c_sz[i] * c_sz[i] * 2);
    for (int i = 0; i < 4; ++i) WoB[i] = (ushort*)alloc((size_t)c_sz[i] * c_sz[i] * 2);
    ushort* WkB = (ushort*)alloc((size_t)2 * GE * 2);
    ushort* WvB = (ushort*)alloc((size_t)2 * GE * 2);

    for (int i = 0; i < 4; ++i) {
        size_t n = (size_t)2 * c_sz[i] * c_sz[i];
        cvtf2b<<<dim3((unsigned)((n / 4 + 255) / 256)), 256, 0, stream>>>(Wq[i], WqB[i], n);
        n = (size_t)c_sz[i] * c_sz[i];
        cvtf2b<<<dim3((unsigned)((n / 4 + 255) / 256)), 256, 0, stream>>>(Wo[i], WoB[i], n);
    }
    cvtf2b<<<dim3(1800), 256, 0, stream>>>(Wk, WkB, 2 * GE);
    cvtf2b<<<dim3(1800), 256, 0, stream>>>(Wv, WvB, 2 * GE);

    // Per-batch dynamic slots (bytes): A bf16 BN ; B bf16 2*BN ; Sc f32 2*GE ; P bf16 2*GE
    const size_t perB = BN * 2 + 2 * BN * 2 + 2 * GE * 4 + 2 * GE * 2;  // 16,957,440
    size_t statik = (off + 255) & ~(size_t)255;
    int NB = 16;
    while (NB > 1 && statik + (size_t)NB * perB + 65536 > ws_size) NB >>= 1;

    ushort* slotA = (ushort*)alloc((size_t)NB * BN * 2);          // G / ctx
    ushort* slotB = (ushort*)alloc((size_t)NB * 2 * BN * 2);      // Y / V
    float*  Sc    = (float*) alloc((size_t)NB * 2 * GE * 4);      // scores f32
    ushort* P     = (ushort*)alloc((size_t)NB * 2 * GE * 2);      // probs bf16
    float*  stats = (float*) alloc((size_t)NB * 2 * 4 * 2 * 4);
    float2v* parts = (float2v*)alloc((size_t)NB * 2 * 4 * 8 * 8);

    for (int b0 = 0; b0 < B_; b0 += NB) {
        // 1) G[b,p,m] = emb_cat^T @ emb_all -> bf16
        for (int i = 0; i < 4; ++i) {
            mgemm<true, true, true, true, 1, false>
                <<<dim3(KV_ / 64, c_sz[i] / 64, NB), 256, 0, stream>>>(
                c_sz[i], KV_, N_, 1.0f,
                emb[i] + (size_t)b0 * N_ * c_sz[i], c_sz[i], (size_t)N_ * c_sz[i], 0,
                emb_all + (size_t)b0 * BN, KV_, BN, 0,
                slotA + (size_t)c_off[i] * KV_, KV_, BN, 0, /*hsel=*/0);
        }

        // 2) Y[b,h] rows c_off.. = Wq_i[h] @ G_i
        for (int i = 0; i < 4; ++i) {
            mgemm<false, true, false, false, 1, false>
                <<<dim3(KV_ / 64, c_sz[i] / 64, NB * H_), 256, 0, stream>>>(
                c_sz[i], KV_, c_sz[i], 1.0f,
                WqB[i], c_sz[i], 0, (size_t)c_sz[i] * c_sz[i],
                slotA + (size_t)c_off[i] * KV_, KV_, BN, 0,
                slotB + (size_t)c_off[i] * KV_, KV_, 2 * BN, BN, /*hsel=*/-1);
        }

        // 3) scores f32 = SCALE * Y @ Wk[h]^T
        mgemm<false, false, false, false, 1, true>
            <<<dim3(KV_ / 64, KV_ / 64, NB * H_), 256, 0, stream>>>(
            KV_, KV_, KV_, SCALE,
            slotB, KV_, 2 * BN, BN,
            WkB, KV_, 0, GE,
            Sc, KV_, 2 * GE, GE, /*hsel=*/-1);

        // 4) two-stage stats + softmax -> P bf16
        normstats1<<<dim3(NB * H_ * 4, 8), 256, 0, stream>>>(Sc, parts);
        normstats2<<<NB * H_ * 4, 64, 0, stream>>>(parts, stats);
        psoftmax<<<NB * H_ * KV_, 256, 0, stream>>>(Sc, P, stats);

        // 5) V bf16 = emb_all @ Wv[h]^T
        mgemm<false, false, true, false, 1, false>
            <<<dim3(KV_ / 64, N_ / 64, NB * H_), 256, 0, stream>>>(
            N_, KV_, KV_, 1.0f,
            emb_all + (size_t)b0 * BN, KV_, BN, 0,
            WvB, KV_, 0, GE,
            slotB, KV_, 2 * BN, BN, /*hsel=*/-1);

        // 6) ctx bf16 = 0.5 * sum_h V[h] @ P[h]^T
        mgemm<false, false, false, false, 2, false>
            <<<dim3(KV_ / 64, N_ / 64, NB), 256, 0, stream>>>(
            N_, KV_, KV_, 0.5f,
            slotB, KV_, 2 * BN, BN,
            P, KV_, 2 * GE, GE,
            slotA, KV_, BN, 0, /*hsel=*/0);

        // 7) out f32 = ctx_i @ Wo_i^T
        for (int i = 0; i < 4; ++i) {
            mgemm<false, false, false, false, 1, true>
                <<<dim3(c_sz[i] / 64, N_ / 64, NB), 256, 0, stream>>>(
                N_, c_sz[i], c_sz[i], 1.0f,
                slotA + c_off[i], KV_, BN, 0,
                WoB[i], c_sz[i], 0, 0,
                out + (size_t)b0 * BN + c_off[i], KV_, BN, 0, /*hsel=*/0);
        }
    }
}

// Round 6
// 982.347 us; speedup vs baseline: 5.6291x; 1.2825x over previous
//
#include <hip/hip_runtime.h>
#include <cmath>

#define B_   16
#define N_   1024
#define KV_  960
#define H_   2

typedef __attribute__((ext_vector_type(8))) short     short8;
typedef __attribute__((ext_vector_type(8))) unsigned short ushort8;
typedef __attribute__((ext_vector_type(4))) unsigned short ushort4v;
typedef __attribute__((ext_vector_type(4))) float     f32x4;
typedef __attribute__((ext_vector_type(4))) float     float4v;
typedef __attribute__((ext_vector_type(2))) float     float2v;

__device__ inline ushort f2b(float f) {
    union { float f; unsigned u; } x; x.f = f;
    unsigned r = x.u + 0x7FFFu + ((x.u >> 16) & 1u);   // RNE
    return (ushort)(r >> 16);
}

// Bijective XCD-chunking swizzle (m204): maps blockIdx.x so that each XCD
// (orig%8) owns a CONTIGUOUS chunk of logical workgroup ids -> L2 locality.
__device__ inline int xcd_swz(int orig, int nwg) {
    int q = nwg >> 3, r = nwg & 7;
    int xcd = orig & 7, idx = orig >> 3;
    return (xcd < r ? xcd * (q + 1) : r * (q + 1) + (xcd - r) * q) + idx;
}

// ---------------------------------------------------------------------------
// Stage a 64(row)x64(k) bf16 tile into LDS [64][72] (144B row stride).
// ---------------------------------------------------------------------------
template<bool TR, bool F32S>
__device__ inline void stage64(const void* __restrict__ src, int ld, int r0, int k0,
                               ushort* __restrict__ lds, int t)
{
#pragma unroll
    for (int rep = 0; rep < 2; ++rep) {
        int idx = t + rep * 256;                      // 0..511, 8 elts each
        if (!TR) {
            int rr = idx >> 3, kc = (idx & 7) << 3;
            ushort8 v;
            if (F32S) {
                const float* s = (const float*)src + (size_t)(r0 + rr) * ld + (k0 + kc);
                float4v f0 = *(const float4v*)s;
                float4v f1 = *(const float4v*)(s + 4);
                v[0] = f2b(f0[0]); v[1] = f2b(f0[1]); v[2] = f2b(f0[2]); v[3] = f2b(f0[3]);
                v[4] = f2b(f1[0]); v[5] = f2b(f1[1]); v[6] = f2b(f1[2]); v[7] = f2b(f1[3]);
            } else {
                v = *(const ushort8*)((const ushort*)src + (size_t)(r0 + rr) * ld + (k0 + kc));
            }
            *(ushort8*)&lds[rr * 72 + kc] = v;
        } else {
            int kk = idx >> 3, rc = (idx & 7) << 3;
            ushort tmp[8];
            if (F32S) {
                const float* s = (const float*)src + (size_t)(k0 + kk) * ld + (r0 + rc);
                float4v f0 = *(const float4v*)s;
                float4v f1 = *(const float4v*)(s + 4);
                tmp[0] = f2b(f0[0]); tmp[1] = f2b(f0[1]); tmp[2] = f2b(f0[2]); tmp[3] = f2b(f0[3]);
                tmp[4] = f2b(f1[0]); tmp[5] = f2b(f1[1]); tmp[6] = f2b(f1[2]); tmp[7] = f2b(f1[3]);
            } else {
                const ushort* s = (const ushort*)src + (size_t)(k0 + kk) * ld + (r0 + rc);
                ushort8 v = *(const ushort8*)s;
#pragma unroll
                for (int j = 0; j < 8; ++j) tmp[j] = v[j];
            }
#pragma unroll
            for (int j = 0; j < 8; ++j) lds[(rc + j) * 72 + kk] = tmp[j];
        }
    }
}

// ---------------------------------------------------------------------------
// 64x64-tile bf16 MFMA GEMM, 1D swizzled grid (gx*gy*gz blocks).
// ---------------------------------------------------------------------------
template<bool ATR, bool BTR, bool AF32, bool BF32, int HSUM, bool OUTF32>
__global__ __launch_bounds__(256)
void mgemm(int gx, int gy, int K, float alpha,
           const void* __restrict__ A, int lda, size_t sAb, size_t sAh,
           const void* __restrict__ Bm, int ldb, size_t sBb, size_t sBh,
           void* __restrict__ C, int ldc, size_t sCb, size_t sCh, int hsel)
{
    __shared__ ushort As[64 * 72];
    __shared__ ushort Bs[64 * 72];
    const int wgid = xcd_swz(blockIdx.x, gridDim.x);
    const int xg = wgid % gx, rem = wgid / gx;
    const int yg = rem % gy, z = rem / gy;
    int b, h;
    if (hsel >= 0) { b = z; h = hsel; } else { b = z >> 1; h = z & 1; }
    const int m0 = yg * 64, n0 = xg * 64;
    const int t = threadIdx.x;
    const int lane = t & 63, wave = t >> 6;
    const int wr = wave >> 1, wc = wave & 1;

    f32x4 zero4 = {0.f, 0.f, 0.f, 0.f};
    f32x4 acc[2][2];
    acc[0][0] = zero4; acc[0][1] = zero4; acc[1][0] = zero4; acc[1][1] = zero4;

    for (int hh = 0; hh < HSUM; ++hh) {
        const int he = (HSUM == 2) ? hh : h;
        const char* Ab = (const char*)A + ((size_t)b * sAb + (size_t)he * sAh) * (AF32 ? 4 : 2);
        const char* Bb = (const char*)Bm + ((size_t)b * sBb + (size_t)he * sBh) * (BF32 ? 4 : 2);
        for (int k0 = 0; k0 < K; k0 += 64) {
            stage64<ATR, AF32>(Ab, lda, m0, k0, As, t);
            stage64<BTR, BF32>(Bb, ldb, n0, k0, Bs, t);
            __syncthreads();
            const int ar = wr * 32 + (lane & 15);
            const int br = wc * 32 + (lane & 15);
            const int kg = (lane >> 4) * 8;
#pragma unroll
            for (int ks = 0; ks < 2; ++ks) {
                short8 a0 = *(const short8*)&As[(ar)      * 72 + ks * 32 + kg];
                short8 a1 = *(const short8*)&As[(ar + 16) * 72 + ks * 32 + kg];
                short8 b0 = *(const short8*)&Bs[(br)      * 72 + ks * 32 + kg];
                short8 b1 = *(const short8*)&Bs[(br + 16) * 72 + ks * 32 + kg];
                acc[0][0] = __builtin_amdgcn_mfma_f32_16x16x32_bf16(a0, b0, acc[0][0], 0, 0, 0);
                acc[0][1] = __builtin_amdgcn_mfma_f32_16x16x32_bf16(a0, b1, acc[0][1], 0, 0, 0);
                acc[1][0] = __builtin_amdgcn_mfma_f32_16x16x32_bf16(a1, b0, acc[1][0], 0, 0, 0);
                acc[1][1] = __builtin_amdgcn_mfma_f32_16x16x32_bf16(a1, b1, acc[1][1], 0, 0, 0);
            }
            __syncthreads();
        }
    }

    char* Cb = (char*)C + ((size_t)b * sCb + (size_t)h * sCh) * (OUTF32 ? 4 : 2);
#pragma unroll
    for (int i = 0; i < 2; ++i)
#pragma unroll
        for (int q = 0; q < 4; ++q) {
            int row = m0 + wr * 32 + i * 16 + (lane >> 4) * 4 + q;
#pragma unroll
            for (int j = 0; j < 2; ++j) {
                int col = n0 + wc * 32 + j * 16 + (lane & 15);
                float v = alpha * acc[i][j][q];
                if (OUTF32) ((float*)Cb)[(size_t)row * ldc + col] = v;
                else        ((ushort*)Cb)[(size_t)row * ldc + col] = f2b(v);
            }
        }
}

// ---------------------------------------------------------------------------
// 96x96-tile bf16 MFMA GEMM (direct operands only), 1D swizzled grid.
// 4 waves 2x2, each wave 48x48 = 3x3 fragments. K multiple of 64.
// ---------------------------------------------------------------------------
template<int HSUM, bool OUTF32>
__global__ __launch_bounds__(256)
void mgemm96(int gx, int gy, int K, float alpha,
             const ushort* __restrict__ A, int lda, size_t sAb, size_t sAh,
             const ushort* __restrict__ Bm, int ldb, size_t sBb, size_t sBh,
             void* __restrict__ C, int ldc, size_t sCb, size_t sCh, int hsel)
{
    __shared__ ushort As[96 * 72];
    __shared__ ushort Bs[96 * 72];
    const int wgid = xcd_swz(blockIdx.x, gridDim.x);
    const int xg = wgid % gx, rem = wgid / gx;
    const int yg = rem % gy, z = rem / gy;
    int b, h;
    if (hsel >= 0) { b = z; h = hsel; } else { b = z >> 1; h = z & 1; }
    const int m0 = yg * 96, n0 = xg * 96;
    const int t = threadIdx.x;
    const int lane = t & 63, wave = t >> 6;
    const int wr = wave >> 1, wc = wave & 1;

    f32x4 zero4 = {0.f, 0.f, 0.f, 0.f};
    f32x4 acc[3][3];
#pragma unroll
    for (int i = 0; i < 3; ++i)
#pragma unroll
        for (int j = 0; j < 3; ++j) acc[i][j] = zero4;

    for (int hh = 0; hh < HSUM; ++hh) {
        const int he = (HSUM == 2) ? hh : h;
        const ushort* Ab = A + (size_t)b * sAb + (size_t)he * sAh;
        const ushort* Bb = Bm + (size_t)b * sBb + (size_t)he * sBh;
        for (int k0 = 0; k0 < K; k0 += 64) {
            // stage 96x64 tiles: 768 ushort8 slots, 256 thr x 3 reps
#pragma unroll
            for (int rep = 0; rep < 3; ++rep) {
                int idx = t + rep * 256;
                int rr = idx >> 3, kc = (idx & 7) << 3;
                *(ushort8*)&As[rr * 72 + kc] =
                    *(const ushort8*)&Ab[(size_t)(m0 + rr) * lda + (k0 + kc)];
                *(ushort8*)&Bs[rr * 72 + kc] =
                    *(const ushort8*)&Bb[(size_t)(n0 + rr) * ldb + (k0 + kc)];
            }
            __syncthreads();
            const int ar = wr * 48 + (lane & 15);
            const int br = wc * 48 + (lane & 15);
            const int kg = (lane >> 4) * 8;
#pragma unroll
            for (int ks = 0; ks < 2; ++ks) {
                short8 av[3], bv[3];
#pragma unroll
                for (int i = 0; i < 3; ++i) {
                    av[i] = *(const short8*)&As[(ar + 16 * i) * 72 + ks * 32 + kg];
                    bv[i] = *(const short8*)&Bs[(br + 16 * i) * 72 + ks * 32 + kg];
                }
#pragma unroll
                for (int i = 0; i < 3; ++i)
#pragma unroll
                    for (int j = 0; j < 3; ++j)
                        acc[i][j] = __builtin_amdgcn_mfma_f32_16x16x32_bf16(av[i], bv[j], acc[i][j], 0, 0, 0);
            }
            __syncthreads();
        }
    }

    char* Cb = (char*)C + ((size_t)b * sCb + (size_t)h * sCh) * (OUTF32 ? 4 : 2);
#pragma unroll
    for (int i = 0; i < 3; ++i)
#pragma unroll
        for (int q = 0; q < 4; ++q) {
            int row = m0 + wr * 48 + i * 16 + (lane >> 4) * 4 + q;
#pragma unroll
            for (int j = 0; j < 3; ++j) {
                int col = n0 + wc * 48 + j * 16 + (lane & 15);
                float v = alpha * acc[i][j][q];
                if (OUTF32) ((float*)Cb)[(size_t)row * ldc + col] = v;
                else        ((ushort*)Cb)[(size_t)row * ldc + col] = f2b(v);
            }
        }
}

// ---------------------------------------------------------------------------
// f32 -> bf16 bulk convert (n % 4 == 0)
// ---------------------------------------------------------------------------
__global__ __launch_bounds__(256)
void cvtf2b(const float* __restrict__ s, ushort* __restrict__ d, size_t n)
{
    size_t i = ((size_t)blockIdx.x * 256 + threadIdx.x) * 4;
    size_t stride = (size_t)gridDim.x * 1024;
    for (; i < n; i += stride) {
        float4v f = *(const float4v*)(s + i);
        ushort4v v;
        v[0] = f2b(f[0]); v[1] = f2b(f[1]); v[2] = f2b(f[2]); v[3] = f2b(f[3]);
        *(ushort4v*)(d + i) = v;
    }
}

// ---------------------------------------------------------------------------
// Wv [2][k][m] f32  ->  WvT [2][m][k] bf16  (32x32 LDS tile transpose)
// grid (30, 30, 2), block (32, 8)
// ---------------------------------------------------------------------------
__global__ __launch_bounds__(256)
void transposeWv(const float* __restrict__ src, ushort* __restrict__ dst)
{
    __shared__ ushort tile[32][33];
    const size_t GE = (size_t)KV_ * KV_;
    int hh = blockIdx.z;
    int k0 = blockIdx.x * 32, m0 = blockIdx.y * 32;
    for (int i = threadIdx.y; i < 32; i += 8)
        tile[i][threadIdx.x] = f2b(src[hh * GE + (size_t)(k0 + i) * KV_ + m0 + threadIdx.x]);
    __syncthreads();
    for (int i = threadIdx.y; i < 32; i += 8)
        dst[hh * GE + (size_t)(m0 + i) * KV_ + k0 + threadIdx.x] = tile[threadIdx.x][i];
}

// ---------------------------------------------------------------------------
// InstanceNorm stats, two-stage deterministic reduction (per (b,h,branch)).
// ---------------------------------------------------------------------------
__global__ __launch_bounds__(256)
void normstats1(const float* __restrict__ S, float2v* __restrict__ partials)
{
    const int z = blockIdx.x, chunk = blockIdx.y;
    const int bh = z >> 2, br = z & 3;
    const int row0[4] = {0, 64, 192, 448};
    const int nch [4] = {1, 2, 4, 8};
    if (chunk >= nch[br]) return;
    const float* p = S + (size_t)bh * (KV_ * KV_)
                       + (size_t)(row0[br] + chunk * 64) * KV_;
    float s = 0.f, s2 = 0.f;
    for (int i = threadIdx.x * 4; i < 64 * KV_; i += 1024) {
        float4v f = *(const float4v*)(p + i);
#pragma unroll
        for (int j = 0; j < 4; ++j) { s += f[j]; s2 += f[j] * f[j]; }
    }
#pragma unroll
    for (int o = 32; o; o >>= 1) {
        s  += __shfl_down(s,  o);
        s2 += __shfl_down(s2, o);
    }
    __shared__ float as[4], bs[4];
    int w = threadIdx.x >> 6, l = threadIdx.x & 63;
    if (l == 0) { as[w] = s; bs[w] = s2; }
    __syncthreads();
    if (threadIdx.x == 0) {
        float2v r;
        r[0] = as[0] + as[1] + as[2] + as[3];
        r[1] = bs[0] + bs[1] + bs[2] + bs[3];
        partials[z * 8 + chunk] = r;
    }
}

__global__ __launch_bounds__(64)
void normstats2(const float2v* __restrict__ partials, float* __restrict__ stats)
{
    const int z = blockIdx.x;
    const int br = z & 3;
    const int nch[4] = {1, 2, 4, 8};
    const int csz[4] = {64, 128, 256, 512};
    if (threadIdx.x == 0) {
        float s = 0.f, s2 = 0.f;
        for (int i = 0; i < nch[br]; ++i) {
            float2v r = partials[z * 8 + i];
            s += r[0]; s2 += r[1];
        }
        const float inv_cnt = 1.0f / (float)(csz[br] * KV_);
        float mu  = s * inv_cnt;
        float var = s2 * inv_cnt - mu * mu;
        stats[2 * z]     = mu;
        stats[2 * z + 1] = rsqrtf(var + 1e-5f);
    }
}

// ---------------------------------------------------------------------------
// Row softmax of normalized scores: read f32 S, write bf16 P.
// ---------------------------------------------------------------------------
__global__ __launch_bounds__(256)
void psoftmax(const float* __restrict__ S, ushort* __restrict__ P,
              const float* __restrict__ stats)
{
    const size_t r  = blockIdx.x;
    const int bh  = (int)(r / KV_);
    const int row = (int)(r % KV_);
    const int br  = (row < 64) ? 0 : (row < 192) ? 1 : (row < 448) ? 2 : 3;
    const float mu = stats[2 * (bh * 4 + br)];
    const float rs = stats[2 * (bh * 4 + br) + 1];
    const float* p = S + r * KV_;
    ushort* q = P + r * KV_;

    const int t = threadIdx.x;
    float x[4];
    float mx = -1e30f;
#pragma unroll
    for (int i = 0; i < 4; ++i) {
        int idx = t + i * 256;
        x[i] = (idx < KV_) ? (p[idx] - mu) * rs : -1e30f;
        mx = fmaxf(mx, x[i]);
    }
#pragma unroll
    for (int o = 1; o < 64; o <<= 1) mx = fmaxf(mx, __shfl_xor(mx, o));
    __shared__ float wmax[4], wsum[4];
    int w = t >> 6, l = t & 63;
    if (l == 0) wmax[w] = mx;
    __syncthreads();
    mx = fmaxf(fmaxf(wmax[0], wmax[1]), fmaxf(wmax[2], wmax[3]));

    float s = 0.f;
#pragma unroll
    for (int i = 0; i < 4; ++i) {
        x[i] = expf(x[i] - mx);
        s += x[i];
    }
#pragma unroll
    for (int o = 1; o < 64; o <<= 1) s += __shfl_xor(s, o);
    if (l == 0) wsum[w] = s;
    __syncthreads();
    s = wsum[0] + wsum[1] + wsum[2] + wsum[3];
    float inv = 1.0f / s;
#pragma unroll
    for (int i = 0; i < 4; ++i) {
        int idx = t + i * 256;
        if (idx < KV_) q[idx] = f2b(x[i] * inv);
    }
}

// ---------------------------------------------------------------------------
extern "C" void kernel_launch(void* const* d_in, const int* in_sizes, int n_in,
                              void* d_out, int out_size, void* d_ws, size_t ws_size,
                              hipStream_t stream)
{
    const float* emb[4] = {(const float*)d_in[0], (const float*)d_in[1],
                           (const float*)d_in[2], (const float*)d_in[3]};
    const float* emb_all = (const float*)d_in[4];
    const float* Wq[4] = {(const float*)d_in[5], (const float*)d_in[7],
                          (const float*)d_in[9], (const float*)d_in[11]};
    const float* Wo[4] = {(const float*)d_in[6], (const float*)d_in[8],
                          (const float*)d_in[10], (const float*)d_in[12]};
    const float* Wk = (const float*)d_in[13];
    const float* Wv = (const float*)d_in[14];
    float* out = (float*)d_out;

    const int c_sz[4]  = {64, 128, 256, 512};
    const int c_off[4] = {0, 64, 192, 448};

    const size_t BN = (size_t)N_ * KV_;   // 983040
    const size_t GE = (size_t)KV_ * KV_;  // 921600
    const float SCALE = 0.03227486121839514f;  // 1/sqrt(960)

    // ---- bump allocator on d_ws
    char* wsp = (char*)d_ws;
    size_t off = 0;
    auto alloc = [&](size_t bytes) -> char* {
        off = (off + 255) & ~(size_t)255;
        char* p = wsp + off;
        off += bytes;
        return p;
    };

    // Static: bf16 weights
    ushort* WqB[4]; ushort* WoB[4];
    for (int i = 0; i < 4; ++i) WqB[i] = (ushort*)alloc((size_t)2 * c_sz[i] * c_sz[i] * 2);
    for (int i = 0; i < 4; ++i) WoB[i] = (ushort*)alloc((size_t)c_sz[i] * c_sz[i] * 2);
    ushort* WkB = (ushort*)alloc((size_t)2 * GE * 2);
    ushort* WvT = (ushort*)alloc((size_t)2 * GE * 2);   // [2][m][k] bf16

    for (int i = 0; i < 4; ++i) {
        size_t n = (size_t)2 * c_sz[i] * c_sz[i];
        cvtf2b<<<dim3((unsigned)((n / 4 + 255) / 256)), 256, 0, stream>>>(Wq[i], WqB[i], n);
        n = (size_t)c_sz[i] * c_sz[i];
        cvtf2b<<<dim3((unsigned)((n / 4 + 255) / 256)), 256, 0, stream>>>(Wo[i], WoB[i], n);
    }
    cvtf2b<<<dim3(1800), 256, 0, stream>>>(Wk, WkB, 2 * GE);
    transposeWv<<<dim3(30, 30, 2), dim3(32, 8), 0, stream>>>(Wv, WvT);

    // Per-batch dynamic slots: A bf16 BN (G/ctx) ; B bf16 2*BN (Y, then R) ;
    // Sc f32 2*GE ; P bf16 2*GE ; EA bf16 BN
    const size_t perB = BN * 2 + 2 * BN * 2 + 2 * GE * 4 + 2 * GE * 2 + BN * 2;
    size_t statik = (off + 255) & ~(size_t)255;
    int NB = 16;
    while (NB > 1 && statik + (size_t)NB * perB + 65536 > ws_size) NB >>= 1;

    ushort* slotA = (ushort*)alloc((size_t)NB * BN * 2);          // G / ctx
    ushort* slotB = (ushort*)alloc((size_t)NB * 2 * BN * 2);      // Y, then R
    float*  Sc    = (float*) alloc((size_t)NB * 2 * GE * 4);      // scores f32
    ushort* P     = (ushort*)alloc((size_t)NB * 2 * GE * 2);      // probs bf16
    ushort* EA    = (ushort*)alloc((size_t)NB * BN * 2);          // emb_all bf16
    float*  stats = (float*) alloc((size_t)NB * 2 * 4 * 2 * 4);
    float2v* parts = (float2v*)alloc((size_t)NB * 2 * 4 * 8 * 8);
    ushort* R = slotB;                                            // [NB][GE]

    for (int b0 = 0; b0 < B_; b0 += NB) {
        // 0) emb_all group -> bf16
        cvtf2b<<<dim3(1800), 256, 0, stream>>>(emb_all + (size_t)b0 * BN, EA, NB * BN);

        // 1) G[b,p,m] = emb_cat^T @ emb_all  (A f32 TR, B = EA bf16 TR) -> bf16
        for (int i = 0; i < 4; ++i) {
            int gx = KV_ / 64, gy = c_sz[i] / 64;
            mgemm<true, true, true, false, 1, false>
                <<<dim3(gx * gy * NB), 256, 0, stream>>>(
                gx, gy, N_, 1.0f,
                emb[i] + (size_t)b0 * N_ * c_sz[i], c_sz[i], (size_t)N_ * c_sz[i], 0,
                EA, KV_, BN, 0,
                slotA + (size_t)c_off[i] * KV_, KV_, BN, 0, /*hsel=*/0);
        }

        // 2) Y[b,h] rows c_off.. = Wq_i[h] @ G_i  (B = G TR)
        for (int i = 0; i < 4; ++i) {
            int gx = KV_ / 64, gy = c_sz[i] / 64;
            mgemm<false, true, false, false, 1, false>
                <<<dim3(gx * gy * NB * H_), 256, 0, stream>>>(
                gx, gy, c_sz[i], 1.0f,
                WqB[i], c_sz[i], 0, (size_t)c_sz[i] * c_sz[i],
                slotA + (size_t)c_off[i] * KV_, KV_, BN, 0,
                slotB + (size_t)c_off[i] * KV_, KV_, 2 * BN, BN, /*hsel=*/-1);
        }

        // 3) scores f32 = SCALE * Y @ Wk[h]^T   (96-tile, direct/direct)
        mgemm96<1, true><<<dim3(10 * 10 * NB * H_), 256, 0, stream>>>(
            10, 10, KV_, SCALE,
            slotB, KV_, 2 * BN, BN,
            WkB, KV_, 0, GE,
            Sc, KV_, 2 * GE, GE, /*hsel=*/-1);

        // 4) two-stage stats + softmax -> P bf16
        normstats1<<<dim3(NB * H_ * 4, 8), 256, 0, stream>>>(Sc, parts);
        normstats2<<<NB * H_ * 4, 64, 0, stream>>>(parts, stats);
        psoftmax<<<NB * H_ * KV_, 256, 0, stream>>>(Sc, P, stats);

        // 5) R[b,p,m] = sum_h P[b,h] @ WvT[h]^T-free  (96-tile, HSUM=2) -> bf16
        //    R[p,m] = sum_k P[p,k] * WvT[m,k]
        mgemm96<2, false><<<dim3(10 * 10 * NB), 256, 0, stream>>>(
            10, 10, KV_, 1.0f,
            P, KV_, 2 * GE, GE,
            WvT, KV_, 0, GE,
            R, KV_, GE, 0, /*hsel=*/0);

        // 6) ctx bf16 = 0.5 * EA @ R^T   (ctx[n,p] = sum_m EA[n,m]*R[p,m])
        {
            int gx = KV_ / 64, gy = N_ / 64;
            mgemm<false, false, false, false, 1, false>
                <<<dim3(gx * gy * NB), 256, 0, stream>>>(
                gx, gy, KV_, 0.5f,
                EA, KV_, BN, 0,
                R, KV_, GE, 0,
                slotA, KV_, BN, 0, /*hsel=*/0);
        }

        // 7) out f32 = ctx_i @ Wo_i^T
        for (int i = 0; i < 4; ++i) {
            int gx = c_sz[i] / 64, gy = N_ / 64;
            mgemm<false, false, false, false, 1, true>
                <<<dim3(gx * gy * NB), 256, 0, stream>>>(
                gx, gy, c_sz[i], 1.0f,
                slotA + c_off[i], KV_, BN, 0,
                WoB[i], c_sz[i], 0, 0,
                out + (size_t)b0 * BN + c_off[i], KV_, BN, 0, /*hsel=*/0);
        }
    }
}

// Round 7
// 708.776 us; speedup vs baseline: 7.8018x; 1.3860x over previous
//
#include <hip/hip_runtime.h>
#include <cmath>

#define B_   16
#define N_   1024
#define KV_  960
#define H_   2
#define LDP  1024                      // padded leading dim for all intermediates
#define PGE  ((size_t)1024 * 1024)    // padded slab stride (elements)

typedef __attribute__((ext_vector_type(8))) short     short8;
typedef __attribute__((ext_vector_type(8))) unsigned short ushort8;
typedef __attribute__((ext_vector_type(4))) unsigned short ushort4v;
typedef __attribute__((ext_vector_type(4))) float     f32x4;
typedef __attribute__((ext_vector_type(4))) float     float4v;
typedef __attribute__((ext_vector_type(2))) float     float2v;

__device__ inline ushort f2b(float f) {
    union { float f; unsigned u; } x; x.f = f;
    unsigned r = x.u + 0x7FFFu + ((x.u >> 16) & 1u);   // RNE
    return (ushort)(r >> 16);
}
__device__ inline float b2f(ushort u) {
    union { unsigned u; float f; } x; x.u = (unsigned)u << 16; return x.f;
}

// Bijective XCD-chunking swizzle (m204).
__device__ inline int xcd_swz(int orig, int nwg) {
    int q = nwg >> 3, r = nwg & 7;
    int xcd = orig & 7, idx = orig >> 3;
    return (xcd < r ? xcd * (q + 1) : r * (q + 1) + (xcd - r) * q) + idx;
}

// async global->LDS, 16B per lane (wave-uniform LDS base + lane*16)
__device__ inline void gload16(const ushort* g, ushort* l) {
    __builtin_amdgcn_global_load_lds(
        (const __attribute__((address_space(1))) void*)g,
        (__attribute__((address_space(3))) void*)l, 16, 0, 0);
}

// ---------------------------------------------------------------------------
// 128x128-tile bf16 MFMA GEMM (m97 structure): BK=32, global_load_lds staging,
// XOR-swizzled LDS chunks (slot = row*4 + (ks ^ ((row>>1)&3))), 2-way-free.
// A: [*][LDP] bf16 k-contig (rows=m). B: [*][LDP] bf16 k-contig (rows=n).
// M,N multiples of 128 (pad rows garbage-safe); K multiple of 32.
// ---------------------------------------------------------------------------
template<int HSUM, bool OUTF32>
__global__ __launch_bounds__(256)
void gemm128(int gx, int gy, int K, float alpha,
             const ushort* __restrict__ A, size_t sAb, size_t sAh,
             const ushort* __restrict__ Bm, size_t sBb, size_t sBh,
             void* __restrict__ C, int ldc, size_t sCb, size_t sCh, int hsel)
{
    __shared__ ushort As[128 * 32];
    __shared__ ushort Bs[128 * 32];
    const int wgid = xcd_swz(blockIdx.x, gridDim.x);
    const int xg = wgid % gx, rem = wgid / gx;
    const int yg = rem % gy, z = rem / gy;
    int b, h;
    if (hsel >= 0) { b = z; h = hsel; } else { b = z >> 1; h = z & 1; }
    const int m0 = yg * 128, n0 = xg * 128;
    const int t = threadIdx.x, lane = t & 63, wave = t >> 6;
    const int wr = wave >> 1, wc = wave & 1;

    f32x4 acc[4][4];
#pragma unroll
    for (int i = 0; i < 4; ++i)
#pragma unroll
        for (int j = 0; j < 4; ++j) acc[i][j] = f32x4{0.f, 0.f, 0.f, 0.f};

    // staging decode (per-lane global source; linear LDS dest)
    int srow[2], skof[2];
#pragma unroll
    for (int j = 0; j < 2; ++j) {
        int s = wave * 64 + j * 256 + lane;
        srow[j] = s >> 2;
        skof[j] = ((s & 3) ^ ((srow[j] >> 1) & 3)) * 8;
    }
    // ds_read offsets (swizzled), ushort units
    int aoff[4], boff[4];
#pragma unroll
    for (int i = 0; i < 4; ++i) {
        int ra = wr * 64 + i * 16 + (lane & 15);
        aoff[i] = ra * 32 + (((lane >> 4) ^ ((ra >> 1) & 3)) * 8);
        int rb = wc * 64 + i * 16 + (lane & 15);
        boff[i] = rb * 32 + (((lane >> 4) ^ ((rb >> 1) & 3)) * 8);
    }

    for (int hh = 0; hh < HSUM; ++hh) {
        const int he = (HSUM == 2) ? hh : h;
        const ushort* Ab = A + (size_t)b * sAb + (size_t)he * sAh;
        const ushort* Bb = Bm + (size_t)b * sBb + (size_t)he * sBh;
        for (int k0 = 0; k0 < K; k0 += 32) {
#pragma unroll
            for (int j = 0; j < 2; ++j) {
                int sbase = wave * 64 + j * 256;
                gload16(Ab + (size_t)(m0 + srow[j]) * LDP + k0 + skof[j], As + sbase * 8);
                gload16(Bb + (size_t)(n0 + srow[j]) * LDP + k0 + skof[j], Bs + sbase * 8);
            }
            __syncthreads();
            short8 a[4], bv[4];
#pragma unroll
            for (int i = 0; i < 4; ++i) {
                a[i]  = *(const short8*)&As[aoff[i]];
                bv[i] = *(const short8*)&Bs[boff[i]];
            }
#pragma unroll
            for (int i = 0; i < 4; ++i)
#pragma unroll
                for (int j = 0; j < 4; ++j)
                    acc[i][j] = __builtin_amdgcn_mfma_f32_16x16x32_bf16(a[i], bv[j], acc[i][j], 0, 0, 0);
            __syncthreads();
        }
    }

    char* Cb = (char*)C + ((size_t)b * sCb + (size_t)h * sCh) * (OUTF32 ? 4 : 2);
#pragma unroll
    for (int i = 0; i < 4; ++i) {
        int row = m0 + wr * 64 + i * 16 + (lane >> 4) * 4;
#pragma unroll
        for (int q = 0; q < 4; ++q)
#pragma unroll
            for (int j = 0; j < 4; ++j) {
                int col = n0 + wc * 64 + j * 16 + (lane & 15);
                float v = alpha * acc[i][j][q];
                if (OUTF32) ((float*)Cb)[(size_t)(row + q) * ldc + col] = v;
                else        ((ushort*)Cb)[(size_t)(row + q) * ldc + col] = f2b(v);
            }
    }
}

// ---------------------------------------------------------------------------
// 64x64 tile staging (kept for small/transposed GEMMs: steps 1, 2, 7)
// ---------------------------------------------------------------------------
template<bool TR, bool F32S>
__device__ inline void stage64(const void* __restrict__ src, int ld, int r0, int k0,
                               ushort* __restrict__ lds, int t)
{
#pragma unroll
    for (int rep = 0; rep < 2; ++rep) {
        int idx = t + rep * 256;
        if (!TR) {
            int rr = idx >> 3, kc = (idx & 7) << 3;
            ushort8 v;
            if (F32S) {
                const float* s = (const float*)src + (size_t)(r0 + rr) * ld + (k0 + kc);
                float4v f0 = *(const float4v*)s;
                float4v f1 = *(const float4v*)(s + 4);
                v[0] = f2b(f0[0]); v[1] = f2b(f0[1]); v[2] = f2b(f0[2]); v[3] = f2b(f0[3]);
                v[4] = f2b(f1[0]); v[5] = f2b(f1[1]); v[6] = f2b(f1[2]); v[7] = f2b(f1[3]);
            } else {
                v = *(const ushort8*)((const ushort*)src + (size_t)(r0 + rr) * ld + (k0 + kc));
            }
            *(ushort8*)&lds[rr * 72 + kc] = v;
        } else {
            int kk = idx >> 3, rc = (idx & 7) << 3;
            ushort tmp[8];
            if (F32S) {
                const float* s = (const float*)src + (size_t)(k0 + kk) * ld + (r0 + rc);
                float4v f0 = *(const float4v*)s;
                float4v f1 = *(const float4v*)(s + 4);
                tmp[0] = f2b(f0[0]); tmp[1] = f2b(f0[1]); tmp[2] = f2b(f0[2]); tmp[3] = f2b(f0[3]);
                tmp[4] = f2b(f1[0]); tmp[5] = f2b(f1[1]); tmp[6] = f2b(f1[2]); tmp[7] = f2b(f1[3]);
            } else {
                const ushort* s = (const ushort*)src + (size_t)(k0 + kk) * ld + (r0 + rc);
                ushort8 v = *(const ushort8*)s;
#pragma unroll
                for (int j = 0; j < 8; ++j) tmp[j] = v[j];
            }
#pragma unroll
            for (int j = 0; j < 8; ++j) lds[(rc + j) * 72 + kk] = tmp[j];
        }
    }
}

template<bool ATR, bool BTR, bool AF32, bool BF32, int HSUM, bool OUTF32>
__global__ __launch_bounds__(256)
void mgemm(int gx, int gy, int K, float alpha,
           const void* __restrict__ A, int lda, size_t sAb, size_t sAh,
           const void* __restrict__ Bm, int ldb, size_t sBb, size_t sBh,
           void* __restrict__ C, int ldc, size_t sCb, size_t sCh, int hsel)
{
    __shared__ ushort As[64 * 72];
    __shared__ ushort Bs[64 * 72];
    const int wgid = xcd_swz(blockIdx.x, gridDim.x);
    const int xg = wgid % gx, rem = wgid / gx;
    const int yg = rem % gy, z = rem / gy;
    int b, h;
    if (hsel >= 0) { b = z; h = hsel; } else { b = z >> 1; h = z & 1; }
    const int m0 = yg * 64, n0 = xg * 64;
    const int t = threadIdx.x;
    const int lane = t & 63, wave = t >> 6;
    const int wr = wave >> 1, wc = wave & 1;

    f32x4 zero4 = {0.f, 0.f, 0.f, 0.f};
    f32x4 acc[2][2];
    acc[0][0] = zero4; acc[0][1] = zero4; acc[1][0] = zero4; acc[1][1] = zero4;

    for (int hh = 0; hh < HSUM; ++hh) {
        const int he = (HSUM == 2) ? hh : h;
        const char* Ab = (const char*)A + ((size_t)b * sAb + (size_t)he * sAh) * (AF32 ? 4 : 2);
        const char* Bb = (const char*)Bm + ((size_t)b * sBb + (size_t)he * sBh) * (BF32 ? 4 : 2);
        for (int k0 = 0; k0 < K; k0 += 64) {
            stage64<ATR, AF32>(Ab, lda, m0, k0, As, t);
            stage64<BTR, BF32>(Bb, ldb, n0, k0, Bs, t);
            __syncthreads();
            const int ar = wr * 32 + (lane & 15);
            const int br = wc * 32 + (lane & 15);
            const int kg = (lane >> 4) * 8;
#pragma unroll
            for (int ks = 0; ks < 2; ++ks) {
                short8 a0 = *(const short8*)&As[(ar)      * 72 + ks * 32 + kg];
                short8 a1 = *(const short8*)&As[(ar + 16) * 72 + ks * 32 + kg];
                short8 b0 = *(const short8*)&Bs[(br)      * 72 + ks * 32 + kg];
                short8 b1 = *(const short8*)&Bs[(br + 16) * 72 + ks * 32 + kg];
                acc[0][0] = __builtin_amdgcn_mfma_f32_16x16x32_bf16(a0, b0, acc[0][0], 0, 0, 0);
                acc[0][1] = __builtin_amdgcn_mfma_f32_16x16x32_bf16(a0, b1, acc[0][1], 0, 0, 0);
                acc[1][0] = __builtin_amdgcn_mfma_f32_16x16x32_bf16(a1, b0, acc[1][0], 0, 0, 0);
                acc[1][1] = __builtin_amdgcn_mfma_f32_16x16x32_bf16(a1, b1, acc[1][1], 0, 0, 0);
            }
            __syncthreads();
        }
    }

    char* Cb = (char*)C + ((size_t)b * sCb + (size_t)h * sCh) * (OUTF32 ? 4 : 2);
#pragma unroll
    for (int i = 0; i < 2; ++i)
#pragma unroll
        for (int q = 0; q < 4; ++q) {
            int row = m0 + wr * 32 + i * 16 + (lane >> 4) * 4 + q;
#pragma unroll
            for (int j = 0; j < 2; ++j) {
                int col = n0 + wc * 32 + j * 16 + (lane & 15);
                float v = alpha * acc[i][j][q];
                if (OUTF32) ((float*)Cb)[(size_t)row * ldc + col] = v;
                else        ((ushort*)Cb)[(size_t)row * ldc + col] = f2b(v);
            }
        }
}

// ---------------------------------------------------------------------------
// f32 -> bf16 dense convert (n % 4 == 0)
// ---------------------------------------------------------------------------
__global__ __launch_bounds__(256)
void cvtf2b(const float* __restrict__ s, ushort* __restrict__ d, size_t n)
{
    size_t i = ((size_t)blockIdx.x * 256 + threadIdx.x) * 4;
    size_t stride = (size_t)gridDim.x * 1024;
    for (; i < n; i += stride) {
        float4v f = *(const float4v*)(s + i);
        ushort4v v;
        v[0] = f2b(f[0]); v[1] = f2b(f[1]); v[2] = f2b(f[2]); v[3] = f2b(f[3]);
        *(ushort4v*)(d + i) = v;
    }
}

// f32 (ld=sld) -> bf16 (ld=dld) re-strided convert; cols=960 (120 x ushort8)
__global__ __launch_bounds__(256)
void cvt_ld(const float* __restrict__ src, int sld, ushort* __restrict__ dst,
            int dld, int total_chunks)
{
    for (int ch = blockIdx.x * 256 + threadIdx.x; ch < total_chunks;
         ch += gridDim.x * 256) {
        int row = ch / 120, c = (ch % 120) * 8;
        const float* s = src + (size_t)row * sld + c;
        float4v f0 = *(const float4v*)s;
        float4v f1 = *(const float4v*)(s + 4);
        ushort8 v;
        v[0] = f2b(f0[0]); v[1] = f2b(f0[1]); v[2] = f2b(f0[2]); v[3] = f2b(f0[3]);
        v[4] = f2b(f1[0]); v[5] = f2b(f1[1]); v[6] = f2b(f1[2]); v[7] = f2b(f1[3]);
        *(ushort8*)(dst + (size_t)row * dld + c) = v;
    }
}

// Wv [2][k][m] f32 (ld 960) -> WvT [2][m][k] bf16 (ld LDP)
__global__ __launch_bounds__(256)
void transposeWv(const float* __restrict__ src, ushort* __restrict__ dst)
{
    __shared__ ushort tile[32][33];
    const size_t GE9 = (size_t)KV_ * KV_;
    int hh = blockIdx.z;
    int k0 = blockIdx.x * 32, m0 = blockIdx.y * 32;
    for (int i = threadIdx.y; i < 32; i += 8)
        tile[i][threadIdx.x] = f2b(src[hh * GE9 + (size_t)(k0 + i) * KV_ + m0 + threadIdx.x]);
    __syncthreads();
    for (int i = threadIdx.y; i < 32; i += 8)
        dst[hh * PGE + (size_t)(m0 + i) * LDP + k0 + threadIdx.x] = tile[threadIdx.x][i];
}

// ---------------------------------------------------------------------------
// InstanceNorm stats on bf16 scores (LD=LDP, real region only), two-stage.
// ---------------------------------------------------------------------------
__global__ __launch_bounds__(256)
void normstats1(const ushort* __restrict__ S, float2v* __restrict__ partials)
{
    const int z = blockIdx.x, chunk = blockIdx.y;
    const int bh = z >> 2, br = z & 3;
    const int row0[4] = {0, 64, 192, 448};
    const int nch [4] = {1, 2, 4, 8};
    if (chunk >= nch[br]) return;
    const ushort* p = S + (size_t)bh * PGE + (size_t)(row0[br] + chunk * 64) * LDP;
    float s = 0.f, s2 = 0.f;
    for (int ci = threadIdx.x; ci < 64 * 120; ci += 256) {
        int row = ci / 120, c = (ci % 120) * 8;
        ushort8 v = *(const ushort8*)(p + (size_t)row * LDP + c);
#pragma unroll
        for (int j = 0; j < 8; ++j) { float f = b2f(v[j]); s += f; s2 += f * f; }
    }
#pragma unroll
    for (int o = 32; o; o >>= 1) {
        s  += __shfl_down(s,  o);
        s2 += __shfl_down(s2, o);
    }
    __shared__ float as[4], bs[4];
    int w = threadIdx.x >> 6, l = threadIdx.x & 63;
    if (l == 0) { as[w] = s; bs[w] = s2; }
    __syncthreads();
    if (threadIdx.x == 0) {
        float2v r;
        r[0] = as[0] + as[1] + as[2] + as[3];
        r[1] = bs[0] + bs[1] + bs[2] + bs[3];
        partials[z * 8 + chunk] = r;
    }
}

__global__ __launch_bounds__(64)
void normstats2(const float2v* __restrict__ partials, float* __restrict__ stats)
{
    const int z = blockIdx.x;
    const int br = z & 3;
    const int nch[4] = {1, 2, 4, 8};
    const int csz[4] = {64, 128, 256, 512};
    if (threadIdx.x == 0) {
        float s = 0.f, s2 = 0.f;
        for (int i = 0; i < nch[br]; ++i) {
            float2v r = partials[z * 8 + i];
            s += r[0]; s2 += r[1];
        }
        const float inv_cnt = 1.0f / (float)(csz[br] * KV_);
        float mu  = s * inv_cnt;
        float var = s2 * inv_cnt - mu * mu;
        stats[2 * z]     = mu;
        stats[2 * z + 1] = rsqrtf(var + 1e-5f);
    }
}

// ---------------------------------------------------------------------------
// Row softmax, in place on bf16 scores (real 960 cols of LDP-stride rows).
// ---------------------------------------------------------------------------
__global__ __launch_bounds__(256)
void psoftmax(ushort* __restrict__ S, const float* __restrict__ stats)
{
    const int r  = blockIdx.x;
    const int bh  = r / KV_;
    const int row = r % KV_;
    const int br  = (row < 64) ? 0 : (row < 192) ? 1 : (row < 448) ? 2 : 3;
    const float mu = stats[2 * (bh * 4 + br)];
    const float rs = stats[2 * (bh * 4 + br) + 1];
    ushort* p = S + (size_t)bh * PGE + (size_t)row * LDP;

    const int t = threadIdx.x;
    float x[4];
    float mx = -1e30f;
#pragma unroll
    for (int i = 0; i < 4; ++i) {
        int idx = t + i * 256;
        x[i] = (idx < KV_) ? (b2f(p[idx]) - mu) * rs : -1e30f;
        mx = fmaxf(mx, x[i]);
    }
#pragma unroll
    for (int o = 1; o < 64; o <<= 1) mx = fmaxf(mx, __shfl_xor(mx, o));
    __shared__ float wmax[4], wsum[4];
    int w = t >> 6, l = t & 63;
    if (l == 0) wmax[w] = mx;
    __syncthreads();
    mx = fmaxf(fmaxf(wmax[0], wmax[1]), fmaxf(wmax[2], wmax[3]));

    float s = 0.f;
#pragma unroll
    for (int i = 0; i < 4; ++i) {
        x[i] = expf(x[i] - mx);
        s += x[i];
    }
#pragma unroll
    for (int o = 1; o < 64; o <<= 1) s += __shfl_xor(s, o);
    if (l == 0) wsum[w] = s;
    __syncthreads();
    s = wsum[0] + wsum[1] + wsum[2] + wsum[3];
    float inv = 1.0f / s;
#pragma unroll
    for (int i = 0; i < 4; ++i) {
        int idx = t + i * 256;
        if (idx < KV_) p[idx] = f2b(x[i] * inv);
    }
}

// ---------------------------------------------------------------------------
extern "C" void kernel_launch(void* const* d_in, const int* in_sizes, int n_in,
                              void* d_out, int out_size, void* d_ws, size_t ws_size,
                              hipStream_t stream)
{
    const float* emb[4] = {(const float*)d_in[0], (const float*)d_in[1],
                           (const float*)d_in[2], (const float*)d_in[3]};
    const float* emb_all = (const float*)d_in[4];
    const float* Wq[4] = {(const float*)d_in[5], (const float*)d_in[7],
                          (const float*)d_in[9], (const float*)d_in[11]};
    const float* Wo[4] = {(const float*)d_in[6], (const float*)d_in[8],
                          (const float*)d_in[10], (const float*)d_in[12]};
    const float* Wk = (const float*)d_in[13];
    const float* Wv = (const float*)d_in[14];
    float* out = (float*)d_out;

    const int c_sz[4]  = {64, 128, 256, 512};
    const int c_off[4] = {0, 64, 192, 448};

    const size_t BN  = (size_t)N_ * KV_;     // 983040 (real out/emb_all stride)
    const size_t GE9 = (size_t)KV_ * KV_;    // 921600
    const float SCALE = 0.03227486121839514f;  // 1/sqrt(960)

    char* wsp = (char*)d_ws;
    size_t off = 0;
    auto alloc = [&](size_t bytes) -> char* {
        off = (off + 255) & ~(size_t)255;
        char* p = wsp + off;
        off += bytes;
        return p;
    };

    // Static: bf16 weights (padded LD for the 128-path operands)
    ushort* WqB[4]; ushort* WoB[4];
    for (int i = 0; i < 4; ++i) WqB[i] = (ushort*)alloc((size_t)2 * c_sz[i] * c_sz[i] * 2);
    for (int i = 0; i < 4; ++i) WoB[i] = (ushort*)alloc((size_t)c_sz[i] * c_sz[i] * 2);
    ushort* WkB = (ushort*)alloc(2 * PGE * 2);   // [2][1024][LDP]
    ushort* WvT = (ushort*)alloc(2 * PGE * 2);   // [2][1024][LDP] (transposed)

    for (int i = 0; i < 4; ++i) {
        size_t n = (size_t)2 * c_sz[i] * c_sz[i];
        cvtf2b<<<dim3((unsigned)((n / 4 + 255) / 256)), 256, 0, stream>>>(Wq[i], WqB[i], n);
        n = (size_t)c_sz[i] * c_sz[i];
        cvtf2b<<<dim3((unsigned)((n / 4 + 255) / 256)), 256, 0, stream>>>(Wo[i], WoB[i], n);
    }
    for (int hh = 0; hh < 2; ++hh)
        cvt_ld<<<dim3(450), 256, 0, stream>>>(Wk + hh * GE9, KV_, WkB + hh * PGE, LDP, 960 * 120);
    transposeWv<<<dim3(30, 30, 2), dim3(32, 8), 0, stream>>>(Wv, WvT);

    // Per-batch slots (bf16, padded): slotA (G2/ctx) PGE ; Y (Y then R) 2*PGE ;
    // Sc (scores->P in place) 2*PGE ; EA PGE   => 6*PGE*2B = 12 MB/batch
    const size_t perB = 6 * PGE * 2;
    size_t statik = (off + 255) & ~(size_t)255;
    int NB = 16;
    while (NB > 1 && statik + (size_t)NB * perB + 65536 > ws_size) NB >>= 1;

    ushort* slotA = (ushort*)alloc((size_t)NB * PGE * 2);       // G2 / ctx
    ushort* Y     = (ushort*)alloc((size_t)NB * 2 * PGE * 2);   // Y, then R
    ushort* Sc    = (ushort*)alloc((size_t)NB * 2 * PGE * 2);   // scores/P in place
    ushort* EA    = (ushort*)alloc((size_t)NB * PGE * 2);       // emb_all bf16 padded
    float*  stats = (float*) alloc((size_t)NB * 2 * 4 * 2 * 4);
    float2v* parts = (float2v*)alloc((size_t)NB * 2 * 4 * 8 * 8);
    ushort* R = Y;                                              // [NB][1024][LDP]

    for (int b0 = 0; b0 < B_; b0 += NB) {
        // 0) emb_all group -> bf16 padded EA [NB][1024][LDP]
        cvt_ld<<<dim3(3840), 256, 0, stream>>>(emb_all + (size_t)b0 * BN, KV_,
                                               EA, LDP, NB * N_ * 120);

        // 1) G2[m,p] = sum_n EA[n,m] * emb[n,p]   (A=EA TR, B=emb TR f32)
        for (int i = 0; i < 4; ++i) {
            int gx = c_sz[i] / 64, gy = KV_ / 64;
            mgemm<true, true, false, true, 1, false>
                <<<dim3(gx * gy * NB), 256, 0, stream>>>(
                gx, gy, N_, 1.0f,
                EA, LDP, PGE, 0,
                emb[i] + (size_t)b0 * N_ * c_sz[i], c_sz[i], (size_t)N_ * c_sz[i], 0,
                slotA + c_off[i], LDP, PGE, 0, /*hsel=*/0);
        }

        // 2) Y[d,k] = Wq_i[h] @ G2 branch cols   (direct/direct 64-tile)
        for (int i = 0; i < 4; ++i) {
            int gx = KV_ / 64, gy = c_sz[i] / 64;
            mgemm<false, false, false, false, 1, false>
                <<<dim3(gx * gy * NB * H_), 256, 0, stream>>>(
                gx, gy, c_sz[i], 1.0f,
                WqB[i], c_sz[i], 0, (size_t)c_sz[i] * c_sz[i],
                slotA + c_off[i], LDP, PGE, 0,
                Y + (size_t)c_off[i] * LDP, LDP, 2 * PGE, PGE, /*hsel=*/-1);
        }

        // 3) scores bf16 = SCALE * Y @ Wk[h]^T   (128-path)
        gemm128<1, false><<<dim3(8 * 8 * NB * H_), 256, 0, stream>>>(
            8, 8, KV_, SCALE,
            Y, 2 * PGE, PGE,
            WkB, 0, PGE,
            Sc, LDP, 2 * PGE, PGE, /*hsel=*/-1);

        // 4) stats + in-place softmax on Sc
        normstats1<<<dim3(NB * H_ * 4, 8), 256, 0, stream>>>(Sc, parts);
        normstats2<<<NB * H_ * 4, 64, 0, stream>>>(parts, stats);
        psoftmax<<<NB * H_ * KV_, 256, 0, stream>>>(Sc, stats);

        // 5) R[p,m] = sum_h P[b,h] @ WvT[h] rows   (128-path, HSUM=2)
        gemm128<2, false><<<dim3(8 * 8 * NB), 256, 0, stream>>>(
            8, 8, KV_, 1.0f,
            Sc, 2 * PGE, PGE,
            WvT, 0, PGE,
            R, LDP, PGE, 0, /*hsel=*/0);

        // 6) ctx[n,p] = 0.5 * EA @ R^T   (128-path)
        gemm128<1, false><<<dim3(8 * 8 * NB), 256, 0, stream>>>(
            8, 8, KV_, 0.5f,
            EA, PGE, 0,
            R, PGE, 0,
            slotA, LDP, PGE, 0, /*hsel=*/0);

        // 7) out f32 = ctx_i @ Wo_i^T   (direct/direct 64-tile)
        for (int i = 0; i < 4; ++i) {
            int gx = c_sz[i] / 64, gy = N_ / 64;
            mgemm<false, false, false, false, 1, true>
                <<<dim3(gx * gy * NB), 256, 0, stream>>>(
                gx, gy, c_sz[i], 1.0f,
                slotA + c_off[i], LDP, PGE, 0,
                WoB[i], c_sz[i], 0, 0,
                out + (size_t)b0 * BN + c_off[i], KV_, BN, 0, /*hsel=*/0);
        }
    }
}

// Round 8
// 646.223 us; speedup vs baseline: 8.5570x; 1.0968x over previous
//
#include <hip/hip_runtime.h>
#include <cmath>

#define B_   16
#define N_   1024
#define KV_  960
#define H_   2
#define LDP  1024                      // padded leading dim for all intermediates
#define PGE  ((size_t)1024 * 1024)    // padded slab stride (elements)

typedef __attribute__((ext_vector_type(8))) short     short8;
typedef __attribute__((ext_vector_type(8))) unsigned short ushort8;
typedef __attribute__((ext_vector_type(4))) unsigned short ushort4v;
typedef __attribute__((ext_vector_type(4))) float     f32x4;
typedef __attribute__((ext_vector_type(4))) float     float4v;
typedef __attribute__((ext_vector_type(2))) float     float2v;

__device__ inline ushort f2b(float f) {
    union { float f; unsigned u; } x; x.f = f;
    unsigned r = x.u + 0x7FFFu + ((x.u >> 16) & 1u);   // RNE
    return (ushort)(r >> 16);
}
__device__ inline float b2f(ushort u) {
    union { unsigned u; float f; } x; x.u = (unsigned)u << 16; return x.f;
}

// Bijective XCD-chunking swizzle (m204).
__device__ inline int xcd_swz(int orig, int nwg) {
    int q = nwg >> 3, r = nwg & 7;
    int xcd = orig & 7, idx = orig >> 3;
    return (xcd < r ? xcd * (q + 1) : r * (q + 1) + (xcd - r) * q) + idx;
}

// async global->LDS, 16B per lane (wave-uniform LDS base + lane*16)
__device__ inline void gload16(const ushort* g, ushort* l) {
    __builtin_amdgcn_global_load_lds(
        (const __attribute__((address_space(1))) void*)g,
        (__attribute__((address_space(3))) void*)l, 16, 0, 0);
}

// ---------------------------------------------------------------------------
// 128x128-tile bf16 MFMA GEMM (m97 structure): BK=32, global_load_lds staging,
// XOR-swizzled LDS chunks, 2-way-free. A: [*][LDP] k-contig rows=m.
// B: [*][LDP] k-contig rows=n. M,N tiles of 128 (pad junk confined); K mult 32.
// ---------------------------------------------------------------------------
template<int HSUM, bool OUTF32>
__global__ __launch_bounds__(256)
void gemm128(int gx, int gy, int K, float alpha,
             const ushort* __restrict__ A, size_t sAb, size_t sAh,
             const ushort* __restrict__ Bm, size_t sBb, size_t sBh,
             void* __restrict__ C, int ldc, size_t sCb, size_t sCh, int hsel)
{
    __shared__ ushort As[128 * 32];
    __shared__ ushort Bs[128 * 32];
    const int wgid = xcd_swz(blockIdx.x, gridDim.x);
    const int xg = wgid % gx, rem = wgid / gx;
    const int yg = rem % gy, z = rem / gy;
    int b, h;
    if (hsel >= 0) { b = z; h = hsel; } else { b = z >> 1; h = z & 1; }
    const int m0 = yg * 128, n0 = xg * 128;
    const int t = threadIdx.x, lane = t & 63, wave = t >> 6;
    const int wr = wave >> 1, wc = wave & 1;

    f32x4 acc[4][4];
#pragma unroll
    for (int i = 0; i < 4; ++i)
#pragma unroll
        for (int j = 0; j < 4; ++j) acc[i][j] = f32x4{0.f, 0.f, 0.f, 0.f};

    // staging decode (per-lane global source; linear LDS dest)
    int srow[2], skof[2];
#pragma unroll
    for (int j = 0; j < 2; ++j) {
        int s = wave * 64 + j * 256 + lane;
        srow[j] = s >> 2;
        skof[j] = ((s & 3) ^ ((srow[j] >> 1) & 3)) * 8;
    }
    // ds_read offsets (swizzled), ushort units
    int aoff[4], boff[4];
#pragma unroll
    for (int i = 0; i < 4; ++i) {
        int ra = wr * 64 + i * 16 + (lane & 15);
        aoff[i] = ra * 32 + (((lane >> 4) ^ ((ra >> 1) & 3)) * 8);
        int rb = wc * 64 + i * 16 + (lane & 15);
        boff[i] = rb * 32 + (((lane >> 4) ^ ((rb >> 1) & 3)) * 8);
    }

    for (int hh = 0; hh < HSUM; ++hh) {
        const int he = (HSUM == 2) ? hh : h;
        const ushort* Ab = A + (size_t)b * sAb + (size_t)he * sAh;
        const ushort* Bb = Bm + (size_t)b * sBb + (size_t)he * sBh;
        for (int k0 = 0; k0 < K; k0 += 32) {
#pragma unroll
            for (int j = 0; j < 2; ++j) {
                int sbase = wave * 64 + j * 256;
                gload16(Ab + (size_t)(m0 + srow[j]) * LDP + k0 + skof[j], As + sbase * 8);
                gload16(Bb + (size_t)(n0 + srow[j]) * LDP + k0 + skof[j], Bs + sbase * 8);
            }
            __syncthreads();
            short8 a[4], bv[4];
#pragma unroll
            for (int i = 0; i < 4; ++i) {
                a[i]  = *(const short8*)&As[aoff[i]];
                bv[i] = *(const short8*)&Bs[boff[i]];
            }
#pragma unroll
            for (int i = 0; i < 4; ++i)
#pragma unroll
                for (int j = 0; j < 4; ++j)
                    acc[i][j] = __builtin_amdgcn_mfma_f32_16x16x32_bf16(a[i], bv[j], acc[i][j], 0, 0, 0);
            __syncthreads();
        }
    }

    char* Cb = (char*)C + ((size_t)b * sCb + (size_t)h * sCh) * (OUTF32 ? 4 : 2);
#pragma unroll
    for (int i = 0; i < 4; ++i) {
        int row = m0 + wr * 64 + i * 16 + (lane >> 4) * 4;
#pragma unroll
        for (int q = 0; q < 4; ++q)
#pragma unroll
            for (int j = 0; j < 4; ++j) {
                int col = n0 + wc * 64 + j * 16 + (lane & 15);
                float v = alpha * acc[i][j][q];
                if (OUTF32) ((float*)Cb)[(size_t)(row + q) * ldc + col] = v;
                else        ((ushort*)Cb)[(size_t)(row + q) * ldc + col] = f2b(v);
            }
    }
}

// ---------------------------------------------------------------------------
// 64x64 tile GEMM (direct staging only now: steps 2, 7)
// ---------------------------------------------------------------------------
template<bool F32S>
__device__ inline void stage64d(const void* __restrict__ src, int ld, int r0, int k0,
                                ushort* __restrict__ lds, int t)
{
#pragma unroll
    for (int rep = 0; rep < 2; ++rep) {
        int idx = t + rep * 256;
        int rr = idx >> 3, kc = (idx & 7) << 3;
        ushort8 v;
        if (F32S) {
            const float* s = (const float*)src + (size_t)(r0 + rr) * ld + (k0 + kc);
            float4v f0 = *(const float4v*)s;
            float4v f1 = *(const float4v*)(s + 4);
            v[0] = f2b(f0[0]); v[1] = f2b(f0[1]); v[2] = f2b(f0[2]); v[3] = f2b(f0[3]);
            v[4] = f2b(f1[0]); v[5] = f2b(f1[1]); v[6] = f2b(f1[2]); v[7] = f2b(f1[3]);
        } else {
            v = *(const ushort8*)((const ushort*)src + (size_t)(r0 + rr) * ld + (k0 + kc));
        }
        *(ushort8*)&lds[rr * 72 + kc] = v;
    }
}

template<bool AF32, bool BF32, int HSUM, bool OUTF32>
__global__ __launch_bounds__(256)
void mgemm(int gx, int gy, int K, float alpha,
           const void* __restrict__ A, int lda, size_t sAb, size_t sAh,
           const void* __restrict__ Bm, int ldb, size_t sBb, size_t sBh,
           void* __restrict__ C, int ldc, size_t sCb, size_t sCh, int hsel)
{
    __shared__ ushort As[64 * 72];
    __shared__ ushort Bs[64 * 72];
    const int wgid = xcd_swz(blockIdx.x, gridDim.x);
    const int xg = wgid % gx, rem = wgid / gx;
    const int yg = rem % gy, z = rem / gy;
    int b, h;
    if (hsel >= 0) { b = z; h = hsel; } else { b = z >> 1; h = z & 1; }
    const int m0 = yg * 64, n0 = xg * 64;
    const int t = threadIdx.x;
    const int lane = t & 63, wave = t >> 6;
    const int wr = wave >> 1, wc = wave & 1;

    f32x4 zero4 = {0.f, 0.f, 0.f, 0.f};
    f32x4 acc[2][2];
    acc[0][0] = zero4; acc[0][1] = zero4; acc[1][0] = zero4; acc[1][1] = zero4;

    for (int hh = 0; hh < HSUM; ++hh) {
        const int he = (HSUM == 2) ? hh : h;
        const char* Ab = (const char*)A + ((size_t)b * sAb + (size_t)he * sAh) * (AF32 ? 4 : 2);
        const char* Bb = (const char*)Bm + ((size_t)b * sBb + (size_t)he * sBh) * (BF32 ? 4 : 2);
        for (int k0 = 0; k0 < K; k0 += 64) {
            stage64d<AF32>(Ab, lda, m0, k0, As, t);
            stage64d<BF32>(Bb, ldb, n0, k0, Bs, t);
            __syncthreads();
            const int ar = wr * 32 + (lane & 15);
            const int br = wc * 32 + (lane & 15);
            const int kg = (lane >> 4) * 8;
#pragma unroll
            for (int ks = 0; ks < 2; ++ks) {
                short8 a0 = *(const short8*)&As[(ar)      * 72 + ks * 32 + kg];
                short8 a1 = *(const short8*)&As[(ar + 16) * 72 + ks * 32 + kg];
                short8 b0 = *(const short8*)&Bs[(br)      * 72 + ks * 32 + kg];
                short8 b1 = *(const short8*)&Bs[(br + 16) * 72 + ks * 32 + kg];
                acc[0][0] = __builtin_amdgcn_mfma_f32_16x16x32_bf16(a0, b0, acc[0][0], 0, 0, 0);
                acc[0][1] = __builtin_amdgcn_mfma_f32_16x16x32_bf16(a0, b1, acc[0][1], 0, 0, 0);
                acc[1][0] = __builtin_amdgcn_mfma_f32_16x16x32_bf16(a1, b0, acc[1][0], 0, 0, 0);
                acc[1][1] = __builtin_amdgcn_mfma_f32_16x16x32_bf16(a1, b1, acc[1][1], 0, 0, 0);
            }
            __syncthreads();
        }
    }

    char* Cb = (char*)C + ((size_t)b * sCb + (size_t)h * sCh) * (OUTF32 ? 4 : 2);
#pragma unroll
    for (int i = 0; i < 2; ++i)
#pragma unroll
        for (int q = 0; q < 4; ++q) {
            int row = m0 + wr * 32 + i * 16 + (lane >> 4) * 4 + q;
#pragma unroll
            for (int j = 0; j < 2; ++j) {
                int col = n0 + wc * 32 + j * 16 + (lane & 15);
                float v = alpha * acc[i][j][q];
                if (OUTF32) ((float*)Cb)[(size_t)row * ldc + col] = v;
                else        ((ushort*)Cb)[(size_t)row * ldc + col] = f2b(v);
            }
        }
}

// ---------------------------------------------------------------------------
// f32 -> bf16 dense convert (n % 4 == 0)
// ---------------------------------------------------------------------------
__global__ __launch_bounds__(256)
void cvtf2b(const float* __restrict__ s, ushort* __restrict__ d, size_t n)
{
    size_t i = ((size_t)blockIdx.x * 256 + threadIdx.x) * 4;
    size_t stride = (size_t)gridDim.x * 1024;
    for (; i < n; i += stride) {
        float4v f = *(const float4v*)(s + i);
        ushort4v v;
        v[0] = f2b(f[0]); v[1] = f2b(f[1]); v[2] = f2b(f[2]); v[3] = f2b(f[3]);
        *(ushort4v*)(d + i) = v;
    }
}

// f32 (ld=sld) -> bf16 (ld=dld) re-strided convert; cols=960 (120 x ushort8)
__global__ __launch_bounds__(256)
void cvt_ld(const float* __restrict__ src, int sld, ushort* __restrict__ dst,
            int dld, int total_chunks)
{
    for (int ch = blockIdx.x * 256 + threadIdx.x; ch < total_chunks;
         ch += gridDim.x * 256) {
        int row = ch / 120, c = (ch % 120) * 8;
        const float* s = src + (size_t)row * sld + c;
        float4v f0 = *(const float4v*)s;
        float4v f1 = *(const float4v*)(s + 4);
        ushort8 v;
        v[0] = f2b(f0[0]); v[1] = f2b(f0[1]); v[2] = f2b(f0[2]); v[3] = f2b(f0[3]);
        v[4] = f2b(f1[0]); v[5] = f2b(f1[1]); v[6] = f2b(f1[2]); v[7] = f2b(f1[3]);
        *(ushort8*)(dst + (size_t)row * dld + c) = v;
    }
}

// ---------------------------------------------------------------------------
// Generic f32 [R][C] -> bf16 [C][R] tile transpose+convert.
// grid (C/32, R/32, Z), block (32,8); per-z strides sSrc/sDst (elements).
// ---------------------------------------------------------------------------
__global__ __launch_bounds__(256)
void tposecvt(const float* __restrict__ src, size_t sSrc, int sld,
              ushort* __restrict__ dst, size_t sDst, int dld)
{
    __shared__ ushort tile[32][33];
    const float* s = src + (size_t)blockIdx.z * sSrc;
    ushort* d = dst + (size_t)blockIdx.z * sDst;
    int c0 = blockIdx.x * 32, r0 = blockIdx.y * 32;
    for (int i = threadIdx.y; i < 32; i += 8)
        tile[i][threadIdx.x] = f2b(s[(size_t)(r0 + i) * sld + c0 + threadIdx.x]);
    __syncthreads();
    for (int i = threadIdx.y; i < 32; i += 8)
        d[(size_t)(c0 + i) * dld + r0 + threadIdx.x] = tile[threadIdx.x][i];
}

// ---------------------------------------------------------------------------
// InstanceNorm stats on bf16 scores (LD=LDP, real region only), two-stage.
// ---------------------------------------------------------------------------
__global__ __launch_bounds__(256)
void normstats1(const ushort* __restrict__ S, float2v* __restrict__ partials)
{
    const int z = blockIdx.x, chunk = blockIdx.y;
    const int bh = z >> 2, br = z & 3;
    const int row0[4] = {0, 64, 192, 448};
    const int nch [4] = {1, 2, 4, 8};
    if (chunk >= nch[br]) return;
    const ushort* p = S + (size_t)bh * PGE + (size_t)(row0[br] + chunk * 64) * LDP;
    float s = 0.f, s2 = 0.f;
    for (int ci = threadIdx.x; ci < 64 * 120; ci += 256) {
        int row = ci / 120, c = (ci % 120) * 8;
        ushort8 v = *(const ushort8*)(p + (size_t)row * LDP + c);
#pragma unroll
        for (int j = 0; j < 8; ++j) { float f = b2f(v[j]); s += f; s2 += f * f; }
    }
#pragma unroll
    for (int o = 32; o; o >>= 1) {
        s  += __shfl_down(s,  o);
        s2 += __shfl_down(s2, o);
    }
    __shared__ float as[4], bs[4];
    int w = threadIdx.x >> 6, l = threadIdx.x & 63;
    if (l == 0) { as[w] = s; bs[w] = s2; }
    __syncthreads();
    if (threadIdx.x == 0) {
        float2v r;
        r[0] = as[0] + as[1] + as[2] + as[3];
        r[1] = bs[0] + bs[1] + bs[2] + bs[3];
        partials[z * 8 + chunk] = r;
    }
}

__global__ __launch_bounds__(64)
void normstats2(const float2v* __restrict__ partials, float* __restrict__ stats)
{
    const int z = blockIdx.x;
    const int br = z & 3;
    const int nch[4] = {1, 2, 4, 8};
    const int csz[4] = {64, 128, 256, 512};
    if (threadIdx.x == 0) {
        float s = 0.f, s2 = 0.f;
        for (int i = 0; i < nch[br]; ++i) {
            float2v r = partials[z * 8 + i];
            s += r[0]; s2 += r[1];
        }
        const float inv_cnt = 1.0f / (float)(csz[br] * KV_);
        float mu  = s * inv_cnt;
        float var = s2 * inv_cnt - mu * mu;
        stats[2 * z]     = mu;
        stats[2 * z + 1] = rsqrtf(var + 1e-5f);
    }
}

// ---------------------------------------------------------------------------
// Row softmax, in place on bf16 scores (real 960 cols of LDP-stride rows).
// ---------------------------------------------------------------------------
__global__ __launch_bounds__(256)
void psoftmax(ushort* __restrict__ S, const float* __restrict__ stats)
{
    const int r  = blockIdx.x;
    const int bh  = r / KV_;
    const int row = r % KV_;
    const int br  = (row < 64) ? 0 : (row < 192) ? 1 : (row < 448) ? 2 : 3;
    const float mu = stats[2 * (bh * 4 + br)];
    const float rs = stats[2 * (bh * 4 + br) + 1];
    ushort* p = S + (size_t)bh * PGE + (size_t)row * LDP;

    const int t = threadIdx.x;
    float x[4];
    float mx = -1e30f;
#pragma unroll
    for (int i = 0; i < 4; ++i) {
        int idx = t + i * 256;
        x[i] = (idx < KV_) ? (b2f(p[idx]) - mu) * rs : -1e30f;
        mx = fmaxf(mx, x[i]);
    }
#pragma unroll
    for (int o = 1; o < 64; o <<= 1) mx = fmaxf(mx, __shfl_xor(mx, o));
    __shared__ float wmax[4], wsum[4];
    int w = t >> 6, l = t & 63;
    if (l == 0) wmax[w] = mx;
    __syncthreads();
    mx = fmaxf(fmaxf(wmax[0], wmax[1]), fmaxf(wmax[2], wmax[3]));

    float s = 0.f;
#pragma unroll
    for (int i = 0; i < 4; ++i) {
        x[i] = expf(x[i] - mx);
        s += x[i];
    }
#pragma unroll
    for (int o = 1; o < 64; o <<= 1) s += __shfl_xor(s, o);
    if (l == 0) wsum[w] = s;
    __syncthreads();
    s = wsum[0] + wsum[1] + wsum[2] + wsum[3];
    float inv = 1.0f / s;
#pragma unroll
    for (int i = 0; i < 4; ++i) {
        int idx = t + i * 256;
        if (idx < KV_) p[idx] = f2b(x[i] * inv);
    }
}

// ---------------------------------------------------------------------------
extern "C" void kernel_launch(void* const* d_in, const int* in_sizes, int n_in,
                              void* d_out, int out_size, void* d_ws, size_t ws_size,
                              hipStream_t stream)
{
    const float* emb[4] = {(const float*)d_in[0], (const float*)d_in[1],
                           (const float*)d_in[2], (const float*)d_in[3]};
    const float* emb_all = (const float*)d_in[4];
    const float* Wq[4] = {(const float*)d_in[5], (const float*)d_in[7],
                          (const float*)d_in[9], (const float*)d_in[11]};
    const float* Wo[4] = {(const float*)d_in[6], (const float*)d_in[8],
                          (const float*)d_in[10], (const float*)d_in[12]};
    const float* Wk = (const float*)d_in[13];
    const float* Wv = (const float*)d_in[14];
    float* out = (float*)d_out;

    const int c_sz[4]  = {64, 128, 256, 512};
    const int c_off[4] = {0, 64, 192, 448};

    const size_t BN  = (size_t)N_ * KV_;     // 983040
    const size_t GE9 = (size_t)KV_ * KV_;    // 921600
    const float SCALE = 0.03227486121839514f;  // 1/sqrt(960)

    char* wsp = (char*)d_ws;
    size_t off = 0;
    auto alloc = [&](size_t bytes) -> char* {
        off = (off + 255) & ~(size_t)255;
        char* p = wsp + off;
        off += bytes;
        return p;
    };

    // Static: bf16 weights (padded LD for the 128-path operands)
    ushort* WqB[4]; ushort* WoB[4];
    for (int i = 0; i < 4; ++i) WqB[i] = (ushort*)alloc((size_t)2 * c_sz[i] * c_sz[i] * 2);
    for (int i = 0; i < 4; ++i) WoB[i] = (ushort*)alloc((size_t)c_sz[i] * c_sz[i] * 2);
    ushort* WkB = (ushort*)alloc(2 * PGE * 2);   // [2][1024][LDP]
    ushort* WvT = (ushort*)alloc(2 * PGE * 2);   // [2][m][k] bf16, LD=LDP

    for (int i = 0; i < 4; ++i) {
        size_t n = (size_t)2 * c_sz[i] * c_sz[i];
        cvtf2b<<<dim3((unsigned)((n / 4 + 255) / 256)), 256, 0, stream>>>(Wq[i], WqB[i], n);
        n = (size_t)c_sz[i] * c_sz[i];
        cvtf2b<<<dim3((unsigned)((n / 4 + 255) / 256)), 256, 0, stream>>>(Wo[i], WoB[i], n);
    }
    for (int hh = 0; hh < 2; ++hh)
        cvt_ld<<<dim3(450), 256, 0, stream>>>(Wk + hh * GE9, KV_, WkB + hh * PGE, LDP, 960 * 120);
    // WvT[h][m][k] = Wv[h][k][m]
    tposecvt<<<dim3(30, 30, 2), dim3(32, 8), 0, stream>>>(Wv, GE9, KV_, WvT, PGE, LDP);

    // Per-batch slots (bf16, padded): slotA PGE ; Y 2*PGE ; Sc 2*PGE ;
    // EA PGE ; EAT PGE ; embT PGE  => 8*PGE*2B = 16 MB/batch
    const size_t perB = 8 * PGE * 2;
    size_t statik = (off + 255) & ~(size_t)255;
    int NB = 16;
    while (NB > 1 && statik + (size_t)NB * perB + 65536 > ws_size) NB >>= 1;

    ushort* slotA = (ushort*)alloc((size_t)NB * PGE * 2);       // G2 / ctx
    ushort* Y     = (ushort*)alloc((size_t)NB * 2 * PGE * 2);   // Y, then R
    ushort* Sc    = (ushort*)alloc((size_t)NB * 2 * PGE * 2);   // scores/P in place
    ushort* EA    = (ushort*)alloc((size_t)NB * PGE * 2);       // emb_all bf16 [n][m]
    ushort* EAT   = (ushort*)alloc((size_t)NB * PGE * 2);       // emb_all^T bf16 [m][n]
    ushort* embT  = (ushort*)alloc((size_t)NB * PGE * 2);       // emb_cat^T bf16 [p][n]
    float*  stats = (float*) alloc((size_t)NB * 2 * 4 * 2 * 4);
    float2v* parts = (float2v*)alloc((size_t)NB * 2 * 4 * 8 * 8);
    ushort* R = Y;                                              // [NB][1024][LDP]

    for (int b0 = 0; b0 < B_; b0 += NB) {
        // 0) EA [n][m] bf16 ; EAT [m][n] ; embT [p][n]
        cvt_ld<<<dim3(3840), 256, 0, stream>>>(emb_all + (size_t)b0 * BN, KV_,
                                               EA, LDP, NB * N_ * 120);
        tposecvt<<<dim3(30, 32, NB), dim3(32, 8), 0, stream>>>(
            emb_all + (size_t)b0 * BN, BN, KV_, EAT, PGE, LDP);
        for (int i = 0; i < 4; ++i)
            tposecvt<<<dim3(c_sz[i] / 32, 32, NB), dim3(32, 8), 0, stream>>>(
                emb[i] + (size_t)b0 * N_ * c_sz[i], (size_t)N_ * c_sz[i], c_sz[i],
                embT + (size_t)c_off[i] * LDP, PGE, LDP);

        // 1) G2[m,p] = sum_n EA[n,m]*emb_cat[n,p]  (single 128-path, K=1024)
        gemm128<1, false><<<dim3(8 * 8 * NB), 256, 0, stream>>>(
            8, 8, N_, 1.0f,
            EAT, PGE, 0,
            embT, PGE, 0,
            slotA, LDP, PGE, 0, /*hsel=*/0);

        // 2) Y[d,k] = Wq_i[h] @ G2 branch cols   (64-tile direct/direct)
        for (int i = 0; i < 4; ++i) {
            int gx = KV_ / 64, gy = c_sz[i] / 64;
            mgemm<false, false, 1, false>
                <<<dim3(gx * gy * NB * H_), 256, 0, stream>>>(
                gx, gy, c_sz[i], 1.0f,
                WqB[i], c_sz[i], 0, (size_t)c_sz[i] * c_sz[i],
                slotA + c_off[i], LDP, PGE, 0,
                Y + (size_t)c_off[i] * LDP, LDP, 2 * PGE, PGE, /*hsel=*/-1);
        }

        // 3) scores bf16 = SCALE * Y @ Wk[h]^T   (128-path)
        gemm128<1, false><<<dim3(8 * 8 * NB * H_), 256, 0, stream>>>(
            8, 8, KV_, SCALE,
            Y, 2 * PGE, PGE,
            WkB, 0, PGE,
            Sc, LDP, 2 * PGE, PGE, /*hsel=*/-1);

        // 4) stats + in-place softmax on Sc
        normstats1<<<dim3(NB * H_ * 4, 8), 256, 0, stream>>>(Sc, parts);
        normstats2<<<NB * H_ * 4, 64, 0, stream>>>(parts, stats);
        psoftmax<<<NB * H_ * KV_, 256, 0, stream>>>(Sc, stats);

        // 5) R[p,m] = sum_h P[b,h] @ WvT[h] rows   (128-path, HSUM=2)
        gemm128<2, false><<<dim3(8 * 8 * NB), 256, 0, stream>>>(
            8, 8, KV_, 1.0f,
            Sc, 2 * PGE, PGE,
            WvT, 0, PGE,
            R, LDP, PGE, 0, /*hsel=*/0);

        // 6) ctx[n,p] = 0.5 * EA @ R^T   (128-path)
        gemm128<1, false><<<dim3(8 * 8 * NB), 256, 0, stream>>>(
            8, 8, KV_, 0.5f,
            EA, PGE, 0,
            R, PGE, 0,
            slotA, LDP, PGE, 0, /*hsel=*/0);

        // 7) out f32 = ctx_i @ Wo_i^T   (64-tile direct/direct)
        for (int i = 0; i < 4; ++i) {
            int gx = c_sz[i] / 64, gy = N_ / 64;
            mgemm<false, false, 1, true>
                <<<dim3(gx * gy * NB), 256, 0, stream>>>(
                gx, gy, c_sz[i], 1.0f,
                slotA + c_off[i], LDP, PGE, 0,
                WoB[i], c_sz[i], 0, 0,
                out + (size_t)b0 * BN + c_off[i], KV_, BN, 0, /*hsel=*/0);
        }
    }
}